// Round 10
// baseline (91.832 us; speedup 1.0000x reference)
//
#include <hip/hip_runtime.h>
#include <hip/hip_bf16.h>

#define B_ 2
#define C_ 128
#define N_ 4096
#define NH_ 4
#define HD_ 32
#define GROUPS_ 32
#define EPS_ 1e-5f
// (1/sqrt(32)) * log2(e): QK^T computed directly in log2 domain
#define SCALE2_ 0.25503486f
#define NCH_ 4           // KV chunks (occupancy lever)
#define CHKV_ 1024       // KV rows per chunk
#define NT_ (CHKV_ / 64) // 64-row KV tiles per chunk

typedef __attribute__((ext_vector_type(4))) float f32x4;
typedef __attribute__((ext_vector_type(8))) short s16x8;
typedef __attribute__((ext_vector_type(2))) unsigned int u32x2;
typedef __attribute__((ext_vector_type(4))) unsigned int u32x4;
typedef unsigned short u16;
typedef unsigned int u32;

static __device__ __forceinline__ u16 f2bf(float f) {
  u32 u = __float_as_uint(f);
  u += 0x7FFFu + ((u >> 16) & 1u);   // RNE
  return (u16)(u >> 16);
}
static __device__ __forceinline__ u32 cvtpk_bf16(float lo, float hi) {
  u32 r;
  asm("v_cvt_pk_bf16_f32 %0, %1, %2" : "=v"(r) : "v"(lo), "v"(hi));
  return r;
}
// raw v_exp_f32: inputs here are bounded (|S*log2e| < ~12), no denorm fixup needed
static __device__ __forceinline__ float fexp2(float x) {
  float r;
  asm("v_exp_f32 %0, %1" : "=v"(r) : "v"(x));
  return r;
}
// unpack u32 holding 2 bf16 -> 2 f32
static __device__ __forceinline__ float bflo(u32 w) { return __uint_as_float(w << 16); }
static __device__ __forceinline__ float bfhi(u32 w) { return __uint_as_float(w & 0xffff0000u); }

// ---------------- GroupNorm -> bf16 xn. One block per (b, group) -------------
__global__ __launch_bounds__(256) void k_groupnorm(
    const float* __restrict__ x, const float* __restrict__ gw,
    const float* __restrict__ gb, u16* __restrict__ xn) {
  const int blk = blockIdx.x;            // b*GROUPS + g
  const int tid = threadIdx.x;
  const size_t base = (size_t)blk * (4 * N_);   // contiguous 16384 elems
  const f32x4* x4 = (const f32x4*)(x + base);
  float s = 0.f, ss = 0.f;
  for (int i = tid; i < 4096; i += 256) {
    f32x4 v = x4[i];
    s  += v.x + v.y + v.z + v.w;
    ss += v.x*v.x + v.y*v.y + v.z*v.z + v.w*v.w;
  }
  for (int off = 32; off; off >>= 1) {
    s  += __shfl_down(s, off);
    ss += __shfl_down(ss, off);
  }
  __shared__ float red[2][4];
  __shared__ float mv[2];
  const int wid = tid >> 6;
  if ((tid & 63) == 0) { red[0][wid] = s; red[1][wid] = ss; }
  __syncthreads();
  if (tid == 0) {
    float S = red[0][0]+red[0][1]+red[0][2]+red[0][3];
    float Q = red[1][0]+red[1][1]+red[1][2]+red[1][3];
    float mu  = S * (1.f/16384.f);
    float var = Q * (1.f/16384.f) - mu*mu;
    mv[0] = mu; mv[1] = rsqrtf(var + EPS_);
  }
  __syncthreads();
  const float mu = mv[0], rs = mv[1];
  const int gi = blk & (GROUPS_ - 1);
  u32x2* xn2 = (u32x2*)(xn + base);
  for (int i = tid; i < 4096; i += 256) {
    const int c = gi*4 + (i >> 10);
    const float a  = gw[c] * rs;
    const float b2 = gb[c] - mu * a;
    f32x4 v = x4[i];
    f32x4 r = v * a + b2;
    u32x2 p = { cvtpk_bf16(r.x, r.y), cvtpk_bf16(r.z, r.w) };
    xn2[i] = p;
  }
}

// ---------------- QKV GEMM: qkv[b,o,n] = qkv_w[o,:]·xn[b,:,n] + qkv_b[o] -----
// xn is bf16; 8 output rows per block (halved L2 traffic vs 4).
__global__ __launch_bounds__(256) void k_gemm_qkv(
    const u16* __restrict__ xn, const float* __restrict__ w,
    const float* __restrict__ bias, float* __restrict__ out) {
  const int tid = threadIdx.x;
  const int n0 = blockIdx.x * 1024 + tid * 4;
  const int o0 = blockIdx.y * 8;
  const int b  = blockIdx.z;
  const u16* xb = xn + (size_t)b * C_ * N_;
  const float* wp = w + (size_t)o0 * C_;
  f32x4 a0 = {0.f,0.f,0.f,0.f}, a1 = a0, a2 = a0, a3 = a0;
  f32x4 a4 = a0, a5 = a0, a6 = a0, a7 = a0;
  #pragma unroll 4
  for (int c = 0; c < C_; ++c) {
    const u32* xr = (const u32*)(xb + (size_t)c * N_ + n0);
    const u32 lo = xr[0], hi = xr[1];
    const f32x4 xv = { bflo(lo), bfhi(lo), bflo(hi), bfhi(hi) };
    a0 += xv * wp[c];
    a1 += xv * wp[C_ + c];
    a2 += xv * wp[2*C_ + c];
    a3 += xv * wp[3*C_ + c];
    a4 += xv * wp[4*C_ + c];
    a5 += xv * wp[5*C_ + c];
    a6 += xv * wp[6*C_ + c];
    a7 += xv * wp[7*C_ + c];
  }
  float* op = out + ((size_t)b * 384 + o0) * N_ + n0;
  *(f32x4*)(op)        = a0 + bias[o0];
  *(f32x4*)(op + N_)   = a1 + bias[o0+1];
  *(f32x4*)(op + 2*N_) = a2 + bias[o0+2];
  *(f32x4*)(op + 3*N_) = a3 + bias[o0+3];
  *(f32x4*)(op + 4*N_) = a4 + bias[o0+4];
  *(f32x4*)(op + 5*N_) = a5 + bias[o0+5];
  *(f32x4*)(op + 6*N_) = a6 + bias[o0+6];
  *(f32x4*)(op + 7*N_) = a7 + bias[o0+7];
}

// ---------------- K transpose+cast: qkv K block [d][m] f32 -> Kt [b][h][m][d] bf16
__global__ __launch_bounds__(256) void k_conv_k(
    const float* __restrict__ qkv, u16* __restrict__ Kt) {
  __shared__ float T[128 * 33];
  const int m0 = blockIdx.x * 128;
  const int h = blockIdx.y, b = blockIdx.z;
  const int tid = threadIdx.x;
  const float* kb = qkv + ((size_t)b * 384 + 128 + h * HD_) * N_;
  #pragma unroll
  for (int rep = 0; rep < 16; ++rep) {
    const int idx = rep * 256 + tid;
    const int dd = idx >> 7, mm = idx & 127;
    T[mm * 33 + dd] = kb[(size_t)dd * N_ + m0 + mm];
  }
  __syncthreads();
  u16* kout = Kt + ((size_t)(b * NH_ + h) * N_ + m0) * HD_;
  #pragma unroll
  for (int rep = 0; rep < 8; ++rep) {
    const int idx = rep * 256 + tid;
    const int mm = idx >> 4, dp = idx & 15;
    u16 v0 = f2bf(T[mm*33 + 2*dp]);
    u16 v1 = f2bf(T[mm*33 + 2*dp + 1]);
    *(u32*)(kout + (size_t)mm * HD_ + 2*dp) = (u32)v0 | ((u32)v1 << 16);
  }
}

// ---------------- V cast: qkv V block f32 -> Vb [b][c=h*32+d][m] bf16 --------
__global__ __launch_bounds__(256) void k_conv_v(
    const float* __restrict__ qkv, u16* __restrict__ Vb) {
  const int i4 = blockIdx.x * 256 + threadIdx.x;     // [0, B*C*N/4)
  const int perb = C_ * N_ / 4;                      // 131072 (pow2)
  const int b = i4 / perb, r = i4 - b * perb;
  const f32x4 v = *(const f32x4*)(qkv + ((size_t)b * 384 + 256) * N_ + (size_t)r * 4);
  u32 p0 = (u32)f2bf(v.x) | ((u32)f2bf(v.y) << 16);
  u32 p1 = (u32)f2bf(v.z) | ((u32)f2bf(v.w) << 16);
  u32* dst = (u32*)(Vb + (size_t)b * C_ * N_ + (size_t)r * 4);
  dst[0] = p0; dst[1] = p1;
}

// ---------------- Flash attention, bf16 MFMA 16x16x32, swapped-QK^T ----------
// LDS-staged K/V tiles (R9 win). This round: XOR-swizzle Kl 16B slots
// (slot ^= (row>>3)&3) -- K frag reads previously hit only 2 bank-quads per
// 16-lane group (row-parity), ~4x serialization on 4 of 8 ds_reads/tile.
// All four read rows (pi, pi+4, pi+32, pi+36) share (row>>3)&3, so reads need
// one precomputed XOR per lane. V [32][72] pad is already conflict-even.
__global__ __launch_bounds__(256) void k_attn(
    const float* __restrict__ qkv, const u16* __restrict__ Kt,
    const u16* __restrict__ Vb, float* __restrict__ Opart,
    float* __restrict__ Lpart) {
  __shared__ u16 Kl[64 * 32];      // [m][d] 4KB, 16B-slot swizzled
  __shared__ u16 Vl[32 * 72];      // [d][m padded] 4.5KB
  const int b = blockIdx.z, h = blockIdx.y;
  const int qt = blockIdx.x & 63, ch = blockIdx.x >> 6;
  const int tid = threadIdx.x;
  const int wid = tid >> 6, lane = tid & 63;
  const int g = lane >> 4, lq = lane & 15;
  const int q0 = qt * 64 + wid * 16;
  const int kv0 = ch * CHKV_;

  // Q B-frag: B[k=d][n=q]; scale*log2e folded in. Loaded once (f32 qkv).
  const float* qbase = qkv + ((size_t)b * 384 + h * HD_) * N_;
  s16x8 qfrag;
  #pragma unroll
  for (int j = 0; j < 8; ++j) {
    float qv = qbase[(size_t)(8*g + j) * N_ + q0 + lq] * SCALE2_;
    qfrag[j] = (short)f2bf(qv);
  }

  const u16* ktb = Kt + (size_t)(b * NH_ + h) * N_ * HD_;         // [m][d]
  const u16* vbb = Vb + ((size_t)b * C_ + h * HD_) * N_;          // [d][m]
  const int pi = ((lq >> 2) << 3) + (lq & 3);   // A-row -> K row permutation

  // staging (coalesced): K = one s16x8/thread (2048 elems), V = one s16x8/thread
  const u16* kst = ktb + (size_t)kv0 * HD_ + tid * 8;        // + tt*64*HD_
  const int vrow = tid >> 3;            // 0..31 (d)
  const int vcol = (tid & 7) * 8;       // 0..56 (m)
  const u16* vst = vbb + (size_t)vrow * N_ + kv0 + vcol;     // + tt*64
  u16* kdst = Kl + ((tid * 8) ^ (((tid >> 5) & 3) * 8));     // swizzled slot
  u16* vdst = Vl + vrow * 72 + vcol;

  // fragment LDS addresses (elements); K slots swizzled by x=(pi>>3)&3
  const int xsw  = (pi >> 3) & 3;
  const int slot = 8 * (g ^ xsw);
  const int ka0 = (pi)      * 32 + slot;
  const int ka1 = (pi + 4)  * 32 + slot;
  const int ka2 = (pi + 32) * 32 + slot;
  const int ka3 = (pi + 36) * 32 + slot;
  const int va0 = lq * 72 + 8*g;
  const int va1 = (lq + 16) * 72 + 8*g;

  const short one_bf = (short)0x3F80;   // bf16 1.0
  const s16x8 onesB = {one_bf, one_bf, one_bf, one_bf,
                       one_bf, one_bf, one_bf, one_bf};

  f32x4 oa0 = {0.f,0.f,0.f,0.f}, oa1 = {0.f,0.f,0.f,0.f};
  f32x4 oL  = {0.f,0.f,0.f,0.f};

  // prologue: stage tile 0
  {
    s16x8 kr = *(const s16x8*)(kst);
    s16x8 vr = *(const s16x8*)(vst);
    *(s16x8*)(kdst) = kr;
    *(s16x8*)(vdst) = vr;
  }
  __syncthreads();

  for (int tt = 0; tt < NT_; ++tt) {
    // issue next-tile loads early (clamped on last iter; rewrite is harmless)
    const int tn = (tt + 1 < NT_) ? (tt + 1) : (NT_ - 1);
    s16x8 kr = *(const s16x8*)(kst + (size_t)tn * 64 * HD_);
    s16x8 vr = *(const s16x8*)(vst + (size_t)tn * 64);

    // fragments from LDS
    const s16x8 ck0 = *(const s16x8*)(Kl + ka0);
    const s16x8 ck1 = *(const s16x8*)(Kl + ka1);
    const s16x8 ck2 = *(const s16x8*)(Kl + ka2);
    const s16x8 ck3 = *(const s16x8*)(Kl + ka3);
    const s16x8 cv0 = *(const s16x8*)(Vl + va0);
    const s16x8 cv1 = *(const s16x8*)(Vl + va1);
    const s16x8 cv2 = *(const s16x8*)(Vl + va0 + 32);
    const s16x8 cv3 = *(const s16x8*)(Vl + va1 + 32);

    const f32x4 z = {0.f,0.f,0.f,0.f};
    f32x4 s0 = __builtin_amdgcn_mfma_f32_16x16x32_bf16(ck0, qfrag, z, 0, 0, 0);
    f32x4 s1 = __builtin_amdgcn_mfma_f32_16x16x32_bf16(ck1, qfrag, z, 0, 0, 0);
    f32x4 s2 = __builtin_amdgcn_mfma_f32_16x16x32_bf16(ck2, qfrag, z, 0, 0, 0);
    f32x4 s3 = __builtin_amdgcn_mfma_f32_16x16x32_bf16(ck3, qfrag, z, 0, 0, 0);

    float p0 = fexp2(s0.x), p1 = fexp2(s0.y), p2 = fexp2(s0.z), p3 = fexp2(s0.w);
    float p4 = fexp2(s1.x), p5 = fexp2(s1.y), p6 = fexp2(s1.z), p7 = fexp2(s1.w);
    float p8 = fexp2(s2.x), p9 = fexp2(s2.y), pa_ = fexp2(s2.z), pb_ = fexp2(s2.w);
    float pc_ = fexp2(s3.x), pd_ = fexp2(s3.y), pe_ = fexp2(s3.z), pf_ = fexp2(s3.w);

    union { u32x4 u; s16x8 s; } pkA, pkB;
    pkA.u.x = cvtpk_bf16(p0, p1);   pkA.u.y = cvtpk_bf16(p2, p3);
    pkA.u.z = cvtpk_bf16(p4, p5);   pkA.u.w = cvtpk_bf16(p6, p7);
    pkB.u.x = cvtpk_bf16(p8, p9);   pkB.u.y = cvtpk_bf16(pa_, pb_);
    pkB.u.z = cvtpk_bf16(pc_, pd_); pkB.u.w = cvtpk_bf16(pe_, pf_);

    oa0 = __builtin_amdgcn_mfma_f32_16x16x32_bf16(pkA.s, cv0, oa0, 0, 0, 0);
    oa1 = __builtin_amdgcn_mfma_f32_16x16x32_bf16(pkA.s, cv1, oa1, 0, 0, 0);
    oL  = __builtin_amdgcn_mfma_f32_16x16x32_bf16(pkA.s, onesB, oL, 0, 0, 0);
    oa0 = __builtin_amdgcn_mfma_f32_16x16x32_bf16(pkB.s, cv2, oa0, 0, 0, 0);
    oa1 = __builtin_amdgcn_mfma_f32_16x16x32_bf16(pkB.s, cv3, oa1, 0, 0, 0);
    oL  = __builtin_amdgcn_mfma_f32_16x16x32_bf16(pkB.s, onesB, oL, 0, 0, 0);

    __syncthreads();                 // all reads of Kl/Vl done
    *(s16x8*)(kdst) = kr;            // overwrite with next tile
    *(s16x8*)(vdst) = vr;
    __syncthreads();                 // next tile visible
  }

  // partial store: Opart[ch][b][h][q][d] (coalesced 64B row chunks), Lpart[ch][b][h][q]
  const int bh = b * NH_ + h;
  float* opb = Opart + ((size_t)ch * (B_ * NH_) + bh) * ((size_t)N_ * HD_);
  #pragma unroll
  for (int r = 0; r < 4; ++r) {
    const int qrow = q0 + g*4 + r;
    opb[(size_t)qrow * HD_ + lq]      = oa0[r];
    opb[(size_t)qrow * HD_ + lq + 16] = oa1[r];
  }
  if (lq == 0) {
    float* lp = Lpart + ((size_t)ch * (B_ * NH_) + bh) * N_ + q0 + g*4;
    lp[0] = oL[0]; lp[1] = oL[1]; lp[2] = oL[2]; lp[3] = oL[3];
  }
}

// ---------------- Combine partials: sum chunks, normalize, transpose, bf16 out
// Grid: 512 blocks = (b,h) x 64 n-tiles; block handles [64 n][32 d].
__global__ __launch_bounds__(256) void k_comb(
    const float* __restrict__ Opart, const float* __restrict__ Lpart,
    u16* __restrict__ O) {
  __shared__ float T[32][65];
  __shared__ float linv[64];
  const int t = threadIdx.x;
  const int nt = blockIdx.x & 63, bh = blockIdx.x >> 6;
  const int n0 = nt * 64;
  const float* opb = Opart + (size_t)bh * ((size_t)N_ * HD_) + (size_t)n0 * HD_;

  f32x4 acc0 = {0.f,0.f,0.f,0.f}, acc1 = acc0;
  #pragma unroll
  for (int c = 0; c < NCH_; ++c) {
    const float* p = opb + (size_t)c * ((size_t)B_ * NH_ * N_ * HD_);
    acc0 += *(const f32x4*)(p + (size_t)t * 4);
    acc1 += *(const f32x4*)(p + (size_t)(t + 256) * 4);
  }
  if (t < 64) {
    float s = 0.f;
    #pragma unroll
    for (int c = 0; c < NCH_; ++c)
      s += Lpart[((size_t)c * (B_ * NH_) + bh) * N_ + n0 + t];
    linv[t] = 1.0f / s;
  }
  __syncthreads();
  {
    int nl = t >> 3, d0 = (t & 7) * 4;
    float iv = linv[nl];
    T[d0][nl] = acc0.x*iv; T[d0+1][nl] = acc0.y*iv;
    T[d0+2][nl] = acc0.z*iv; T[d0+3][nl] = acc0.w*iv;
    nl = (t + 256) >> 3; d0 = (t & 7) * 4;
    iv = linv[nl];
    T[d0][nl] = acc1.x*iv; T[d0+1][nl] = acc1.y*iv;
    T[d0+2][nl] = acc1.z*iv; T[d0+3][nl] = acc1.w*iv;
  }
  __syncthreads();
  u16* ob = O + (size_t)bh * (HD_ * N_) + n0;   // O[b][h*32+d][n] bf16
  const int row = t >> 3, col = (t & 7) * 8;
  u32x4 pk = { cvtpk_bf16(T[row][col],   T[row][col+1]),
               cvtpk_bf16(T[row][col+2], T[row][col+3]),
               cvtpk_bf16(T[row][col+4], T[row][col+5]),
               cvtpk_bf16(T[row][col+6], T[row][col+7]) };
  *(u32x4*)(ob + (size_t)row * N_ + col) = pk;
}

// ---------------- Out GEMM + bias + residual (O bf16 in, y f32 out) ----------
__global__ __launch_bounds__(256) void k_gemm_out(
    const u16* __restrict__ O, const float* __restrict__ w,
    const float* __restrict__ bias, const float* __restrict__ x,
    float* __restrict__ y) {
  const int tid = threadIdx.x;
  const int n0 = blockIdx.x * 1024 + tid * 4;
  const int o0 = blockIdx.y * 4;
  const int b  = blockIdx.z;
  const u16* ob = O + (size_t)b * C_ * N_;
  const float* wp = w + (size_t)o0 * C_;
  f32x4 a0 = {0.f,0.f,0.f,0.f}, a1 = a0, a2 = a0, a3 = a0;
  #pragma unroll 4
  for (int c = 0; c < C_; ++c) {
    const u32* xr = (const u32*)(ob + (size_t)c * N_ + n0);
    const u32 lo = xr[0], hi = xr[1];
    const f32x4 xv = { bflo(lo), bfhi(lo), bflo(hi), bfhi(hi) };
    a0 += xv * wp[c];
    a1 += xv * wp[C_ + c];
    a2 += xv * wp[2*C_ + c];
    a3 += xv * wp[3*C_ + c];
  }
  const size_t yo = ((size_t)b * C_ + o0) * N_ + n0;
  *(f32x4*)(y + yo)        = a0 + bias[o0]   + *(const f32x4*)(x + yo);
  *(f32x4*)(y + yo + N_)   = a1 + bias[o0+1] + *(const f32x4*)(x + yo + N_);
  *(f32x4*)(y + yo + 2*N_) = a2 + bias[o0+2] + *(const f32x4*)(x + yo + 2*N_);
  *(f32x4*)(y + yo + 3*N_) = a3 + bias[o0+3] + *(const f32x4*)(x + yo + 3*N_);
}

extern "C" void kernel_launch(void* const* d_in, const int* in_sizes, int n_in,
                              void* d_out, int out_size, void* d_ws, size_t ws_size,
                              hipStream_t stream) {
  const float* x     = (const float*)d_in[0];
  const float* gn_w  = (const float*)d_in[1];
  const float* gn_b  = (const float*)d_in[2];
  const float* qkv_w = (const float*)d_in[3];
  const float* qkv_b = (const float*)d_in[4];
  const float* out_w = (const float*)d_in[5];
  const float* out_b = (const float*)d_in[6];
  float* y = (float*)d_out;

  // ws layout (float offsets):
  //   xn/O bf16 : [0, 1048576)        xn = [b][c][n] bf16 (2MB); O reuses (1MB)
  //   qkv  f32  : [1048576, 4194304)  12 MB
  //   Kt   bf16 : [4194304, 4718592)   2 MB
  //   Vb   bf16 : [4718592, 5242880)   2 MB
  //   Opart f32 : [5242880, 9437184)  16 MB  (4 chunks x [b][h][4096][32])
  //   Lpart f32 : [9437184, 9568256)  0.5 MB
  float* ws  = (float*)d_ws;
  u16*   xn  = (u16*)ws;
  float* qkv = ws + 1048576;
  u16*   Kt  = (u16*)(ws + 4194304);
  u16*   Vb  = (u16*)(ws + 4718592);
  float* Opart = ws + 5242880;
  float* Lpart = ws + 9437184;
  u16*   O   = xn;                       // alias (xn dead after k_gemm_qkv)

  k_groupnorm<<<dim3(B_ * GROUPS_), 256, 0, stream>>>(x, gn_w, gn_b, xn);
  k_gemm_qkv <<<dim3(4, 48, B_),    256, 0, stream>>>(xn, qkv_w, qkv_b, qkv);
  k_conv_k   <<<dim3(32, NH_, B_),  256, 0, stream>>>(qkv, Kt);
  k_conv_v   <<<dim3(1024),         256, 0, stream>>>(qkv, Vb);
  k_attn     <<<dim3(64 * NCH_, NH_, B_), 256, 0, stream>>>(qkv, Kt, Vb, Opart, Lpart);
  k_comb     <<<dim3(512),          256, 0, stream>>>(Opart, Lpart, O);
  k_gemm_out <<<dim3(4, 32, B_),    256, 0, stream>>>(O, out_w, out_b, x, y);
}

// Round 11
// 85.434 us; speedup vs baseline: 1.0749x; 1.0749x over previous
//
#include <hip/hip_runtime.h>
#include <hip/hip_bf16.h>

#define B_ 2
#define C_ 128
#define N_ 4096
#define NH_ 4
#define HD_ 32
#define GROUPS_ 32
#define EPS_ 1e-5f
// (1/sqrt(32)) * log2(e): QK^T computed directly in log2 domain
#define SCALE2_ 0.25503486f
#define NCH_ 4           // KV chunks (occupancy lever)
#define CHKV_ 1024       // KV rows per chunk
#define NT_ (CHKV_ / 64) // 64-row KV tiles per chunk

typedef __attribute__((ext_vector_type(4))) float f32x4;
typedef __attribute__((ext_vector_type(8))) short s16x8;
typedef __attribute__((ext_vector_type(2))) unsigned int u32x2;
typedef __attribute__((ext_vector_type(4))) unsigned int u32x4;
typedef unsigned short u16;
typedef unsigned int u32;

static __device__ __forceinline__ u32 cvtpk_bf16(float lo, float hi) {
  u32 r;
  asm("v_cvt_pk_bf16_f32 %0, %1, %2" : "=v"(r) : "v"(lo), "v"(hi));
  return r;
}
// raw v_exp_f32: inputs bounded (|S*log2e| < ~12), no denorm fixup needed
static __device__ __forceinline__ float fexp2(float x) {
  float r;
  asm("v_exp_f32 %0, %1" : "=v"(r) : "v"(x));
  return r;
}
// unpack u32 holding 2 bf16 -> 2 f32
static __device__ __forceinline__ float bflo(u32 w) { return __uint_as_float(w << 16); }
static __device__ __forceinline__ float bfhi(u32 w) { return __uint_as_float(w & 0xffff0000u); }

// ---------------- GroupNorm -> bf16 xn. One block per (b, group) -------------
__global__ __launch_bounds__(256) void k_groupnorm(
    const float* __restrict__ x, const float* __restrict__ gw,
    const float* __restrict__ gb, u16* __restrict__ xn) {
  const int blk = blockIdx.x;            // b*GROUPS + g
  const int tid = threadIdx.x;
  const size_t base = (size_t)blk * (4 * N_);   // contiguous 16384 elems
  const f32x4* x4 = (const f32x4*)(x + base);
  float s = 0.f, ss = 0.f;
  for (int i = tid; i < 4096; i += 256) {
    f32x4 v = x4[i];
    s  += v.x + v.y + v.z + v.w;
    ss += v.x*v.x + v.y*v.y + v.z*v.z + v.w*v.w;
  }
  for (int off = 32; off; off >>= 1) {
    s  += __shfl_down(s, off);
    ss += __shfl_down(ss, off);
  }
  __shared__ float red[2][4];
  __shared__ float mv[2];
  const int wid = tid >> 6;
  if ((tid & 63) == 0) { red[0][wid] = s; red[1][wid] = ss; }
  __syncthreads();
  if (tid == 0) {
    float S = red[0][0]+red[0][1]+red[0][2]+red[0][3];
    float Q = red[1][0]+red[1][1]+red[1][2]+red[1][3];
    float mu  = S * (1.f/16384.f);
    float var = Q * (1.f/16384.f) - mu*mu;
    mv[0] = mu; mv[1] = rsqrtf(var + EPS_);
  }
  __syncthreads();
  const float mu = mv[0], rs = mv[1];
  const int gi = blk & (GROUPS_ - 1);
  u32x2* xn2 = (u32x2*)(xn + base);
  for (int i = tid; i < 4096; i += 256) {
    const int c = gi*4 + (i >> 10);
    const float a  = gw[c] * rs;
    const float b2 = gb[c] - mu * a;
    f32x4 v = x4[i];
    f32x4 r = v * a + b2;
    u32x2 p = { cvtpk_bf16(r.x, r.y), cvtpk_bf16(r.z, r.w) };
    xn2[i] = p;
  }
}

// ---------------- QKV GEMM -> bf16 qkvb; Q rows pre-scaled by SCALE2_ --------
// Writes [b][o][n] bf16: o<128 = Q*SCALE2_, 128..255 = K, 256..383 = V.
__global__ __launch_bounds__(256) void k_gemm_qkv(
    const u16* __restrict__ xn, const float* __restrict__ w,
    const float* __restrict__ bias, u16* __restrict__ out) {
  const int tid = threadIdx.x;
  const int n0 = blockIdx.x * 1024 + tid * 4;
  const int o0 = blockIdx.y * 8;
  const int b  = blockIdx.z;
  const u16* xb = xn + (size_t)b * C_ * N_;
  const float* wp = w + (size_t)o0 * C_;
  f32x4 a0 = {0.f,0.f,0.f,0.f}, a1 = a0, a2 = a0, a3 = a0;
  f32x4 a4 = a0, a5 = a0, a6 = a0, a7 = a0;
  #pragma unroll 4
  for (int c = 0; c < C_; ++c) {
    const u32* xr = (const u32*)(xb + (size_t)c * N_ + n0);
    const u32 lo = xr[0], hi = xr[1];
    const f32x4 xv = { bflo(lo), bfhi(lo), bflo(hi), bfhi(hi) };
    a0 += xv * wp[c];
    a1 += xv * wp[C_ + c];
    a2 += xv * wp[2*C_ + c];
    a3 += xv * wp[3*C_ + c];
    a4 += xv * wp[4*C_ + c];
    a5 += xv * wp[5*C_ + c];
    a6 += xv * wp[6*C_ + c];
    a7 += xv * wp[7*C_ + c];
  }
  const float sc = (o0 < 128) ? SCALE2_ : 1.0f;   // uniform per block (8-row blocks)
  u16* op = out + ((size_t)b * 384 + o0) * N_ + n0;
  f32x4 acc[8] = {a0,a1,a2,a3,a4,a5,a6,a7};
  #pragma unroll
  for (int i = 0; i < 8; ++i) {
    f32x4 r = (acc[i] + bias[o0 + i]) * sc;
    u32x2 p = { cvtpk_bf16(r.x, r.y), cvtpk_bf16(r.z, r.w) };
    *(u32x2*)(op + (size_t)i * N_) = p;
  }
}

// ---------------- K transpose: qkvb K block [d][m] bf16 -> Kt [b][h][m][d] ----
__global__ __launch_bounds__(256) void k_conv_k(
    const u16* __restrict__ qkvb, u16* __restrict__ Kt) {
  __shared__ u16 T[32][136];
  const int m0 = blockIdx.x * 128;
  const int h = blockIdx.y, b = blockIdx.z;
  const int tid = threadIdx.x;
  const u16* kb = qkvb + ((size_t)b * 384 + 128 + h * HD_) * N_;
  #pragma unroll
  for (int rep = 0; rep < 2; ++rep) {
    const int idx = rep * 256 + tid;
    const int dd = idx >> 4, mm = (idx & 15) * 8;
    *(s16x8*)&T[dd][mm] = *(const s16x8*)(kb + (size_t)dd * N_ + m0 + mm);
  }
  __syncthreads();
  u16* kout = Kt + ((size_t)(b * NH_ + h) * N_ + m0) * HD_;
  #pragma unroll
  for (int rep = 0; rep < 2; ++rep) {
    const int idx = rep * 256 + tid;
    const int mm = idx >> 2, d8 = (idx & 3) * 8;
    u32x4 pk;
    pk.x = (u32)T[d8][mm]   | ((u32)T[d8+1][mm] << 16);
    pk.y = (u32)T[d8+2][mm] | ((u32)T[d8+3][mm] << 16);
    pk.z = (u32)T[d8+4][mm] | ((u32)T[d8+5][mm] << 16);
    pk.w = (u32)T[d8+6][mm] | ((u32)T[d8+7][mm] << 16);
    *(u32x4*)(kout + (size_t)mm * HD_ + d8) = pk;
  }
}

// ---------------- Flash attention: 2 q-tiles per wave, LDS-staged K/V --------
// R10 analysis: LDS b128 ops are a ~12cyc/wave structural floor and K/V frags
// are identical across waves; exp is quarter-rate. So amortize: each wave does
// TWO 16-row q-tiles (q0, q0+64) per K/V tile -> same 10 LDS ops feed 2x MFMA
// and 2x exp. K slots XOR-swizzled (slot ^= (row>>3)&3); V [32][72] padded.
// S^T trick: lane (g,lq) holds P[q][m0+8g+j] = PV A-frag. Denominator via MFMA
// with all-ones B. No max tracking (|S*log2e| bounded); partials to Opart/Lpart.
__global__ __launch_bounds__(256) void k_attn(
    const u16* __restrict__ qkvb, const u16* __restrict__ Kt,
    float* __restrict__ Opart, float* __restrict__ Lpart) {
  __shared__ u16 Kl[64 * 32];      // [m][d] 4KB, 16B-slot swizzled
  __shared__ u16 Vl[32 * 72];      // [d][m padded] 4.5KB
  const int b = blockIdx.z, h = blockIdx.y;
  const int qt = blockIdx.x & 31, ch = blockIdx.x >> 5;
  const int tid = threadIdx.x;
  const int wid = tid >> 6, lane = tid & 63;
  const int g = lane >> 4, lq = lane & 15;
  const int q0 = qt * 128 + wid * 16;        // second tile at q0+64
  const int kv0 = ch * CHKV_;

  // Q B-frags (bf16, pre-scaled): one-time scattered u16 loads
  const u16* qb = qkvb + ((size_t)b * 384 + h * HD_) * N_;
  s16x8 qfA, qfB;
  #pragma unroll
  for (int j = 0; j < 8; ++j) {
    qfA[j] = (short)qb[(size_t)(8*g + j) * N_ + q0 + lq];
    qfB[j] = (short)qb[(size_t)(8*g + j) * N_ + q0 + 64 + lq];
  }

  const u16* ktb = Kt + (size_t)(b * NH_ + h) * N_ * HD_;            // [m][d]
  const u16* vbb = qkvb + ((size_t)b * 384 + 256 + h * HD_) * N_;    // [d][m]
  const int pi = ((lq >> 2) << 3) + (lq & 3);   // A-row -> K row permutation

  // staging (coalesced): K = one s16x8/thread, V = one s16x8/thread
  const u16* kst = ktb + (size_t)kv0 * HD_ + tid * 8;        // + tt*64*HD_
  const int vrow = tid >> 3;            // 0..31 (d)
  const int vcol = (tid & 7) * 8;       // 0..56 (m)
  const u16* vst = vbb + (size_t)vrow * N_ + kv0 + vcol;     // + tt*64
  u16* kdst = Kl + ((tid * 8) ^ (((tid >> 5) & 3) * 8));     // swizzled slot
  u16* vdst = Vl + vrow * 72 + vcol;

  // fragment LDS addresses (elements); K slots swizzled by x=(pi>>3)&3
  const int xsw  = (pi >> 3) & 3;
  const int slot = 8 * (g ^ xsw);
  const int ka0 = (pi)      * 32 + slot;
  const int ka1 = (pi + 4)  * 32 + slot;
  const int ka2 = (pi + 32) * 32 + slot;
  const int ka3 = (pi + 36) * 32 + slot;
  const int va0 = lq * 72 + 8*g;
  const int va1 = (lq + 16) * 72 + 8*g;

  const short one_bf = (short)0x3F80;   // bf16 1.0
  const s16x8 onesB = {one_bf, one_bf, one_bf, one_bf,
                       one_bf, one_bf, one_bf, one_bf};

  f32x4 oa0A = {0.f,0.f,0.f,0.f}, oa1A = oa0A, oLA = oa0A;
  f32x4 oa0B = oa0A, oa1B = oa0A, oLB = oa0A;

  // prologue: stage tile 0
  {
    s16x8 kr = *(const s16x8*)(kst);
    s16x8 vr = *(const s16x8*)(vst);
    *(s16x8*)(kdst) = kr;
    *(s16x8*)(vdst) = vr;
  }
  __syncthreads();

  for (int tt = 0; tt < NT_; ++tt) {
    // issue next-tile loads early (clamped on last iter; rewrite is harmless)
    const int tn = (tt + 1 < NT_) ? (tt + 1) : (NT_ - 1);
    s16x8 kr = *(const s16x8*)(kst + (size_t)tn * 64 * HD_);
    s16x8 vr = *(const s16x8*)(vst + (size_t)tn * 64);

    // fragments from LDS (shared by both q-tiles)
    const s16x8 ck0 = *(const s16x8*)(Kl + ka0);
    const s16x8 ck1 = *(const s16x8*)(Kl + ka1);
    const s16x8 ck2 = *(const s16x8*)(Kl + ka2);
    const s16x8 ck3 = *(const s16x8*)(Kl + ka3);
    const s16x8 cv0 = *(const s16x8*)(Vl + va0);
    const s16x8 cv1 = *(const s16x8*)(Vl + va1);
    const s16x8 cv2 = *(const s16x8*)(Vl + va0 + 32);
    const s16x8 cv3 = *(const s16x8*)(Vl + va1 + 32);

    const f32x4 z = {0.f,0.f,0.f,0.f};
    // ---- q-tile A ----
    {
      f32x4 s0 = __builtin_amdgcn_mfma_f32_16x16x32_bf16(ck0, qfA, z, 0, 0, 0);
      f32x4 s1 = __builtin_amdgcn_mfma_f32_16x16x32_bf16(ck1, qfA, z, 0, 0, 0);
      f32x4 s2 = __builtin_amdgcn_mfma_f32_16x16x32_bf16(ck2, qfA, z, 0, 0, 0);
      f32x4 s3 = __builtin_amdgcn_mfma_f32_16x16x32_bf16(ck3, qfA, z, 0, 0, 0);
      float p0 = fexp2(s0.x), p1 = fexp2(s0.y), p2 = fexp2(s0.z), p3 = fexp2(s0.w);
      float p4 = fexp2(s1.x), p5 = fexp2(s1.y), p6 = fexp2(s1.z), p7 = fexp2(s1.w);
      float p8 = fexp2(s2.x), p9 = fexp2(s2.y), pa_ = fexp2(s2.z), pb_ = fexp2(s2.w);
      float pc_ = fexp2(s3.x), pd_ = fexp2(s3.y), pe_ = fexp2(s3.z), pf_ = fexp2(s3.w);
      union { u32x4 u; s16x8 s; } pkA, pkB;
      pkA.u.x = cvtpk_bf16(p0, p1);   pkA.u.y = cvtpk_bf16(p2, p3);
      pkA.u.z = cvtpk_bf16(p4, p5);   pkA.u.w = cvtpk_bf16(p6, p7);
      pkB.u.x = cvtpk_bf16(p8, p9);   pkB.u.y = cvtpk_bf16(pa_, pb_);
      pkB.u.z = cvtpk_bf16(pc_, pd_); pkB.u.w = cvtpk_bf16(pe_, pf_);
      oa0A = __builtin_amdgcn_mfma_f32_16x16x32_bf16(pkA.s, cv0, oa0A, 0, 0, 0);
      oa1A = __builtin_amdgcn_mfma_f32_16x16x32_bf16(pkA.s, cv1, oa1A, 0, 0, 0);
      oLA  = __builtin_amdgcn_mfma_f32_16x16x32_bf16(pkA.s, onesB, oLA, 0, 0, 0);
      oa0A = __builtin_amdgcn_mfma_f32_16x16x32_bf16(pkB.s, cv2, oa0A, 0, 0, 0);
      oa1A = __builtin_amdgcn_mfma_f32_16x16x32_bf16(pkB.s, cv3, oa1A, 0, 0, 0);
      oLA  = __builtin_amdgcn_mfma_f32_16x16x32_bf16(pkB.s, onesB, oLA, 0, 0, 0);
    }
    // ---- q-tile B ----
    {
      f32x4 s0 = __builtin_amdgcn_mfma_f32_16x16x32_bf16(ck0, qfB, z, 0, 0, 0);
      f32x4 s1 = __builtin_amdgcn_mfma_f32_16x16x32_bf16(ck1, qfB, z, 0, 0, 0);
      f32x4 s2 = __builtin_amdgcn_mfma_f32_16x16x32_bf16(ck2, qfB, z, 0, 0, 0);
      f32x4 s3 = __builtin_amdgcn_mfma_f32_16x16x32_bf16(ck3, qfB, z, 0, 0, 0);
      float p0 = fexp2(s0.x), p1 = fexp2(s0.y), p2 = fexp2(s0.z), p3 = fexp2(s0.w);
      float p4 = fexp2(s1.x), p5 = fexp2(s1.y), p6 = fexp2(s1.z), p7 = fexp2(s1.w);
      float p8 = fexp2(s2.x), p9 = fexp2(s2.y), pa_ = fexp2(s2.z), pb_ = fexp2(s2.w);
      float pc_ = fexp2(s3.x), pd_ = fexp2(s3.y), pe_ = fexp2(s3.z), pf_ = fexp2(s3.w);
      union { u32x4 u; s16x8 s; } pkA, pkB;
      pkA.u.x = cvtpk_bf16(p0, p1);   pkA.u.y = cvtpk_bf16(p2, p3);
      pkA.u.z = cvtpk_bf16(p4, p5);   pkA.u.w = cvtpk_bf16(p6, p7);
      pkB.u.x = cvtpk_bf16(p8, p9);   pkB.u.y = cvtpk_bf16(pa_, pb_);
      pkB.u.z = cvtpk_bf16(pc_, pd_); pkB.u.w = cvtpk_bf16(pe_, pf_);
      oa0B = __builtin_amdgcn_mfma_f32_16x16x32_bf16(pkA.s, cv0, oa0B, 0, 0, 0);
      oa1B = __builtin_amdgcn_mfma_f32_16x16x32_bf16(pkA.s, cv1, oa1B, 0, 0, 0);
      oLB  = __builtin_amdgcn_mfma_f32_16x16x32_bf16(pkA.s, onesB, oLB, 0, 0, 0);
      oa0B = __builtin_amdgcn_mfma_f32_16x16x32_bf16(pkB.s, cv2, oa0B, 0, 0, 0);
      oa1B = __builtin_amdgcn_mfma_f32_16x16x32_bf16(pkB.s, cv3, oa1B, 0, 0, 0);
      oLB  = __builtin_amdgcn_mfma_f32_16x16x32_bf16(pkB.s, onesB, oLB, 0, 0, 0);
    }

    __syncthreads();                 // all reads of Kl/Vl done
    *(s16x8*)(kdst) = kr;            // overwrite with next tile
    *(s16x8*)(vdst) = vr;
    __syncthreads();                 // next tile visible
  }

  // partial store: Opart[ch][b][h][q][d], Lpart[ch][b][h][q]
  const int bh = b * NH_ + h;
  float* opb = Opart + ((size_t)ch * (B_ * NH_) + bh) * ((size_t)N_ * HD_);
  #pragma unroll
  for (int r = 0; r < 4; ++r) {
    const int qrow = q0 + g*4 + r;
    opb[(size_t)qrow * HD_ + lq]             = oa0A[r];
    opb[(size_t)qrow * HD_ + lq + 16]        = oa1A[r];
    opb[(size_t)(qrow + 64) * HD_ + lq]      = oa0B[r];
    opb[(size_t)(qrow + 64) * HD_ + lq + 16] = oa1B[r];
  }
  if (lq == 0) {
    float* lp = Lpart + ((size_t)ch * (B_ * NH_) + bh) * N_ + q0 + g*4;
    lp[0] = oLA[0]; lp[1] = oLA[1]; lp[2] = oLA[2]; lp[3] = oLA[3];
    lp[64] = oLB[0]; lp[65] = oLB[1]; lp[66] = oLB[2]; lp[67] = oLB[3];
  }
}

// ---------------- Combine partials: sum chunks, normalize, transpose, bf16 out
// Grid: 512 blocks = (b,h) x 64 n-tiles; block handles [64 n][32 d].
__global__ __launch_bounds__(256) void k_comb(
    const float* __restrict__ Opart, const float* __restrict__ Lpart,
    u16* __restrict__ O) {
  __shared__ float T[32][65];
  __shared__ float linv[64];
  const int t = threadIdx.x;
  const int nt = blockIdx.x & 63, bh = blockIdx.x >> 6;
  const int n0 = nt * 64;
  const float* opb = Opart + (size_t)bh * ((size_t)N_ * HD_) + (size_t)n0 * HD_;

  f32x4 acc0 = {0.f,0.f,0.f,0.f}, acc1 = acc0;
  #pragma unroll
  for (int c = 0; c < NCH_; ++c) {
    const float* p = opb + (size_t)c * ((size_t)B_ * NH_ * N_ * HD_);
    acc0 += *(const f32x4*)(p + (size_t)t * 4);
    acc1 += *(const f32x4*)(p + (size_t)(t + 256) * 4);
  }
  if (t < 64) {
    float s = 0.f;
    #pragma unroll
    for (int c = 0; c < NCH_; ++c)
      s += Lpart[((size_t)c * (B_ * NH_) + bh) * N_ + n0 + t];
    linv[t] = 1.0f / s;
  }
  __syncthreads();
  {
    int nl = t >> 3, d0 = (t & 7) * 4;
    float iv = linv[nl];
    T[d0][nl] = acc0.x*iv; T[d0+1][nl] = acc0.y*iv;
    T[d0+2][nl] = acc0.z*iv; T[d0+3][nl] = acc0.w*iv;
    nl = (t + 256) >> 3; d0 = (t & 7) * 4;
    iv = linv[nl];
    T[d0][nl] = acc1.x*iv; T[d0+1][nl] = acc1.y*iv;
    T[d0+2][nl] = acc1.z*iv; T[d0+3][nl] = acc1.w*iv;
  }
  __syncthreads();
  u16* ob = O + (size_t)bh * (HD_ * N_) + n0;   // O[b][h*32+d][n] bf16
  const int row = t >> 3, col = (t & 7) * 8;
  u32x4 pk = { cvtpk_bf16(T[row][col],   T[row][col+1]),
               cvtpk_bf16(T[row][col+2], T[row][col+3]),
               cvtpk_bf16(T[row][col+4], T[row][col+5]),
               cvtpk_bf16(T[row][col+6], T[row][col+7]) };
  *(u32x4*)(ob + (size_t)row * N_ + col) = pk;
}

// ---------------- Out GEMM + bias + residual (O bf16 in, y f32 out) ----------
__global__ __launch_bounds__(256) void k_gemm_out(
    const u16* __restrict__ O, const float* __restrict__ w,
    const float* __restrict__ bias, const float* __restrict__ x,
    float* __restrict__ y) {
  const int tid = threadIdx.x;
  const int n0 = blockIdx.x * 1024 + tid * 4;
  const int o0 = blockIdx.y * 4;
  const int b  = blockIdx.z;
  const u16* ob = O + (size_t)b * C_ * N_;
  const float* wp = w + (size_t)o0 * C_;
  f32x4 a0 = {0.f,0.f,0.f,0.f}, a1 = a0, a2 = a0, a3 = a0;
  #pragma unroll 4
  for (int c = 0; c < C_; ++c) {
    const u32* xr = (const u32*)(ob + (size_t)c * N_ + n0);
    const u32 lo = xr[0], hi = xr[1];
    const f32x4 xv = { bflo(lo), bfhi(lo), bflo(hi), bfhi(hi) };
    a0 += xv * wp[c];
    a1 += xv * wp[C_ + c];
    a2 += xv * wp[2*C_ + c];
    a3 += xv * wp[3*C_ + c];
  }
  const size_t yo = ((size_t)b * C_ + o0) * N_ + n0;
  *(f32x4*)(y + yo)        = a0 + bias[o0]   + *(const f32x4*)(x + yo);
  *(f32x4*)(y + yo + N_)   = a1 + bias[o0+1] + *(const f32x4*)(x + yo + N_);
  *(f32x4*)(y + yo + 2*N_) = a2 + bias[o0+2] + *(const f32x4*)(x + yo + 2*N_);
  *(f32x4*)(y + yo + 3*N_) = a3 + bias[o0+3] + *(const f32x4*)(x + yo + 3*N_);
}

extern "C" void kernel_launch(void* const* d_in, const int* in_sizes, int n_in,
                              void* d_out, int out_size, void* d_ws, size_t ws_size,
                              hipStream_t stream) {
  const float* x     = (const float*)d_in[0];
  const float* gn_w  = (const float*)d_in[1];
  const float* gn_b  = (const float*)d_in[2];
  const float* qkv_w = (const float*)d_in[3];
  const float* qkv_b = (const float*)d_in[4];
  const float* out_w = (const float*)d_in[5];
  const float* out_b = (const float*)d_in[6];
  float* y = (float*)d_out;

  // ws layout (float offsets):
  //   xn    bf16: [0, 524288)            2 MB
  //   qkvb  bf16: [524288, 2097152)      6 MB  (Q scaled | K | V) ; O aliases after attn
  //   Kt    bf16: [2097152, 2621440)     2 MB
  //   Opart f32 : [2621440, 6815744)    16 MB  (4 chunks x [b][h][4096][32])
  //   Lpart f32 : [6815744, 6946816)   0.5 MB
  float* ws  = (float*)d_ws;
  u16*   xn   = (u16*)ws;
  u16*   qkvb = (u16*)(ws + 524288);
  u16*   Kt   = (u16*)(ws + 2097152);
  float* Opart = ws + 2621440;
  float* Lpart = ws + 6815744;
  u16*   O    = qkvb;                    // alias (qkvb dead after k_attn)

  k_groupnorm<<<dim3(B_ * GROUPS_), 256, 0, stream>>>(x, gn_w, gn_b, xn);
  k_gemm_qkv <<<dim3(4, 48, B_),    256, 0, stream>>>(xn, qkv_w, qkv_b, qkvb);
  k_conv_k   <<<dim3(32, NH_, B_),  256, 0, stream>>>(qkvb, Kt);
  k_attn     <<<dim3(32 * NCH_, NH_, B_), 256, 0, stream>>>(qkvb, Kt, Opart, Lpart);
  k_comb     <<<dim3(512),          256, 0, stream>>>(Opart, Lpart, O);
  k_gemm_out <<<dim3(4, 32, B_),    256, 0, stream>>>(O, out_w, out_b, x, y);
}

// Round 13
// 79.805 us; speedup vs baseline: 1.1507x; 1.0705x over previous
//
#include <hip/hip_runtime.h>
#include <hip/hip_bf16.h>

#define B_ 2
#define C_ 128
#define N_ 4096
#define NH_ 4
#define HD_ 32
#define GROUPS_ 32
#define EPS_ 1e-5f
// (1/sqrt(32)) * log2(e): QK^T computed directly in log2 domain
#define SCALE2_ 0.25503486f
#define NCH_ 4           // KV chunks
#define CHKV_ 1024       // KV rows per chunk
#define NT_ (CHKV_ / 64) // 64-row KV tiles per chunk

typedef __attribute__((ext_vector_type(2))) float f32x2;
typedef __attribute__((ext_vector_type(4))) float f32x4;
typedef __attribute__((ext_vector_type(8))) short s16x8;
typedef __attribute__((ext_vector_type(2))) unsigned int u32x2;
typedef __attribute__((ext_vector_type(4))) unsigned int u32x4;
typedef unsigned short u16;
typedef unsigned int u32;

static __device__ __forceinline__ u32 cvtpk_bf16(float lo, float hi) {
  u32 r;
  asm("v_cvt_pk_bf16_f32 %0, %1, %2" : "=v"(r) : "v"(lo), "v"(hi));
  return r;
}
// raw v_exp_f32: inputs bounded (|S*log2e| < ~12), no denorm fixup needed
static __device__ __forceinline__ float fexp2(float x) {
  float r;
  asm("v_exp_f32 %0, %1" : "=v"(r) : "v"(x));
  return r;
}
// unpack u32 holding 2 bf16 -> 2 f32 (low halfword = first element)
static __device__ __forceinline__ float bflo(u32 w) { return __uint_as_float(w << 16); }
static __device__ __forceinline__ float bfhi(u32 w) { return __uint_as_float(w & 0xffff0000u); }

// ---------------- GroupNorm -> bf16 xn. One block per (b, group) -------------
__global__ __launch_bounds__(256) void k_groupnorm(
    const float* __restrict__ x, const float* __restrict__ gw,
    const float* __restrict__ gb, u16* __restrict__ xn) {
  const int blk = blockIdx.x;            // b*GROUPS + g
  const int tid = threadIdx.x;
  const size_t base = (size_t)blk * (4 * N_);   // contiguous 16384 elems
  const f32x4* x4 = (const f32x4*)(x + base);
  float s = 0.f, ss = 0.f;
  for (int i = tid; i < 4096; i += 256) {
    f32x4 v = x4[i];
    s  += v.x + v.y + v.z + v.w;
    ss += v.x*v.x + v.y*v.y + v.z*v.z + v.w*v.w;
  }
  for (int off = 32; off; off >>= 1) {
    s  += __shfl_down(s, off);
    ss += __shfl_down(ss, off);
  }
  __shared__ float red[2][4];
  __shared__ float mv[2];
  const int wid = tid >> 6;
  if ((tid & 63) == 0) { red[0][wid] = s; red[1][wid] = ss; }
  __syncthreads();
  if (tid == 0) {
    float S = red[0][0]+red[0][1]+red[0][2]+red[0][3];
    float Q = red[1][0]+red[1][1]+red[1][2]+red[1][3];
    float mu  = S * (1.f/16384.f);
    float var = Q * (1.f/16384.f) - mu*mu;
    mv[0] = mu; mv[1] = rsqrtf(var + EPS_);
  }
  __syncthreads();
  const float mu = mv[0], rs = mv[1];
  const int gi = blk & (GROUPS_ - 1);
  u32x2* xn2 = (u32x2*)(xn + base);
  for (int i = tid; i < 4096; i += 256) {
    const int c = gi*4 + (i >> 10);
    const float a  = gw[c] * rs;
    const float b2 = gb[c] - mu * a;
    f32x4 v = x4[i];
    f32x4 r = v * a + b2;
    u32x2 p = { cvtpk_bf16(r.x, r.y), cvtpk_bf16(r.z, r.w) };
    xn2[i] = p;
  }
}

// ---------------- QKV GEMM -> bf16; K rows written TRANSPOSED to Kt ----------
// Grid (8, 48, B): n-block 512, o-block 8 -> 768 blocks (3/CU, balanced).
// o0<128: Q*(SCALE2_) -> qkvb rows. o0 in [128,256): -> Kt[b][h][m][d] only.
// o0>=256: V -> qkvb rows.   (verified concretely: Kt[(b,h,m,d)] = row 128+32h+d, col m)
__global__ __launch_bounds__(256) void k_gemm_qkv(
    const u16* __restrict__ xn, const float* __restrict__ w,
    const float* __restrict__ bias, u16* __restrict__ qkvb,
    u16* __restrict__ Kt) {
  const int tid = threadIdx.x;
  const int n0 = blockIdx.x * 512 + tid * 2;
  const int o0 = blockIdx.y * 8;
  const int b  = blockIdx.z;
  const u16* xb = xn + (size_t)b * C_ * N_;
  const float* wp = w + (size_t)o0 * C_;
  float ax[8] = {0,0,0,0,0,0,0,0};
  float ay[8] = {0,0,0,0,0,0,0,0};
  #pragma unroll 4
  for (int c = 0; c < C_; ++c) {
    const u32 wv = *(const u32*)(xb + (size_t)c * N_ + n0);
    const float x0 = bflo(wv), x1 = bfhi(wv);
    #pragma unroll
    for (int i = 0; i < 8; ++i) {
      const float wi = wp[(size_t)i * C_ + c];
      ax[i] += x0 * wi;
      ay[i] += x1 * wi;
    }
  }
  #pragma unroll
  for (int i = 0; i < 8; ++i) {
    const float bi = bias[o0 + i];
    ax[i] += bi; ay[i] += bi;
  }
  if (o0 < 128) {            // Q: scale and write rows
    u16* op = qkvb + ((size_t)b * 384 + o0) * N_ + n0;
    #pragma unroll
    for (int i = 0; i < 8; ++i)
      *(u32*)(op + (size_t)i * N_) = cvtpk_bf16(ax[i] * SCALE2_, ay[i] * SCALE2_);
  } else if (o0 < 256) {     // K: transposed into Kt[b][h][m][d]
    const int h  = (o0 - 128) >> 5;
    const int d8 = (o0 - 128) & 31;
    u16* kb = Kt + (size_t)(b * NH_ + h) * N_ * HD_ + d8;
    u32x4 pk0 = { cvtpk_bf16(ax[0], ax[1]), cvtpk_bf16(ax[2], ax[3]),
                  cvtpk_bf16(ax[4], ax[5]), cvtpk_bf16(ax[6], ax[7]) };
    u32x4 pk1 = { cvtpk_bf16(ay[0], ay[1]), cvtpk_bf16(ay[2], ay[3]),
                  cvtpk_bf16(ay[4], ay[5]), cvtpk_bf16(ay[6], ay[7]) };
    *(u32x4*)(kb + (size_t)n0 * HD_)       = pk0;
    *(u32x4*)(kb + (size_t)(n0 + 1) * HD_) = pk1;
  } else {                   // V: write rows
    u16* op = qkvb + ((size_t)b * 384 + o0) * N_ + n0;
    #pragma unroll
    for (int i = 0; i < 8; ++i)
      *(u32*)(op + (size_t)i * N_) = cvtpk_bf16(ax[i], ay[i]);
  }
}

// ---------------- Flash attention: EXACT R11 version (passed @85us) ----------
// 2 q-tiles/wave, single LDS buffer, two barriers/tile, no min-waves bound.
__global__ __launch_bounds__(256) void k_attn(
    const u16* __restrict__ qkvb, const u16* __restrict__ Kt,
    float* __restrict__ Opart, float* __restrict__ Lpart) {
  __shared__ u16 Kl[64 * 32];      // [m][d] 4KB, 16B-slot swizzled
  __shared__ u16 Vl[32 * 72];      // [d][m padded] 4.5KB
  const int b = blockIdx.z, h = blockIdx.y;
  const int qt = blockIdx.x & 31, ch = blockIdx.x >> 5;
  const int tid = threadIdx.x;
  const int wid = tid >> 6, lane = tid & 63;
  const int g = lane >> 4, lq = lane & 15;
  const int q0 = qt * 128 + wid * 16;        // second tile at q0+64
  const int kv0 = ch * CHKV_;

  // Q B-frags (bf16, pre-scaled): one-time scattered u16 loads
  const u16* qb = qkvb + ((size_t)b * 384 + h * HD_) * N_;
  s16x8 qfA, qfB;
  #pragma unroll
  for (int j = 0; j < 8; ++j) {
    qfA[j] = (short)qb[(size_t)(8*g + j) * N_ + q0 + lq];
    qfB[j] = (short)qb[(size_t)(8*g + j) * N_ + q0 + 64 + lq];
  }

  const u16* ktb = Kt + (size_t)(b * NH_ + h) * N_ * HD_;            // [m][d]
  const u16* vbb = qkvb + ((size_t)b * 384 + 256 + h * HD_) * N_;    // [d][m]
  const int pi = ((lq >> 2) << 3) + (lq & 3);   // A-row -> K row permutation

  // staging (coalesced): K = one s16x8/thread, V = one s16x8/thread
  const u16* kst = ktb + (size_t)kv0 * HD_ + tid * 8;        // + tt*64*HD_
  const int vrow = tid >> 3;            // 0..31 (d)
  const int vcol = (tid & 7) * 8;       // 0..56 (m)
  const u16* vst = vbb + (size_t)vrow * N_ + kv0 + vcol;     // + tt*64
  u16* kdst = Kl + ((tid * 8) ^ (((tid >> 5) & 3) * 8));     // swizzled slot
  u16* vdst = Vl + vrow * 72 + vcol;

  // fragment LDS addresses (elements); K slots swizzled by x=(pi>>3)&3
  const int xsw  = (pi >> 3) & 3;
  const int slot = 8 * (g ^ xsw);
  const int ka0 = (pi)      * 32 + slot;
  const int ka1 = (pi + 4)  * 32 + slot;
  const int ka2 = (pi + 32) * 32 + slot;
  const int ka3 = (pi + 36) * 32 + slot;
  const int va0 = lq * 72 + 8*g;
  const int va1 = (lq + 16) * 72 + 8*g;

  const short one_bf = (short)0x3F80;   // bf16 1.0
  const s16x8 onesB = {one_bf, one_bf, one_bf, one_bf,
                       one_bf, one_bf, one_bf, one_bf};

  f32x4 oa0A = {0.f,0.f,0.f,0.f}, oa1A = oa0A, oLA = oa0A;
  f32x4 oa0B = oa0A, oa1B = oa0A, oLB = oa0A;

  // prologue: stage tile 0
  {
    s16x8 kr = *(const s16x8*)(kst);
    s16x8 vr = *(const s16x8*)(vst);
    *(s16x8*)(kdst) = kr;
    *(s16x8*)(vdst) = vr;
  }
  __syncthreads();

  for (int tt = 0; tt < NT_; ++tt) {
    // issue next-tile loads early (clamped on last iter; rewrite is harmless)
    const int tn = (tt + 1 < NT_) ? (tt + 1) : (NT_ - 1);
    s16x8 kr = *(const s16x8*)(kst + (size_t)tn * 64 * HD_);
    s16x8 vr = *(const s16x8*)(vst + (size_t)tn * 64);

    // fragments from LDS (shared by both q-tiles)
    const s16x8 ck0 = *(const s16x8*)(Kl + ka0);
    const s16x8 ck1 = *(const s16x8*)(Kl + ka1);
    const s16x8 ck2 = *(const s16x8*)(Kl + ka2);
    const s16x8 ck3 = *(const s16x8*)(Kl + ka3);
    const s16x8 cv0 = *(const s16x8*)(Vl + va0);
    const s16x8 cv1 = *(const s16x8*)(Vl + va1);
    const s16x8 cv2 = *(const s16x8*)(Vl + va0 + 32);
    const s16x8 cv3 = *(const s16x8*)(Vl + va1 + 32);

    const f32x4 z = {0.f,0.f,0.f,0.f};
    // ---- q-tile A ----
    {
      f32x4 s0 = __builtin_amdgcn_mfma_f32_16x16x32_bf16(ck0, qfA, z, 0, 0, 0);
      f32x4 s1 = __builtin_amdgcn_mfma_f32_16x16x32_bf16(ck1, qfA, z, 0, 0, 0);
      f32x4 s2 = __builtin_amdgcn_mfma_f32_16x16x32_bf16(ck2, qfA, z, 0, 0, 0);
      f32x4 s3 = __builtin_amdgcn_mfma_f32_16x16x32_bf16(ck3, qfA, z, 0, 0, 0);
      float p0 = fexp2(s0.x), p1 = fexp2(s0.y), p2 = fexp2(s0.z), p3 = fexp2(s0.w);
      float p4 = fexp2(s1.x), p5 = fexp2(s1.y), p6 = fexp2(s1.z), p7 = fexp2(s1.w);
      float p8 = fexp2(s2.x), p9 = fexp2(s2.y), pa_ = fexp2(s2.z), pb_ = fexp2(s2.w);
      float pc_ = fexp2(s3.x), pd_ = fexp2(s3.y), pe_ = fexp2(s3.z), pf_ = fexp2(s3.w);
      union { u32x4 u; s16x8 s; } pkA, pkB;
      pkA.u.x = cvtpk_bf16(p0, p1);   pkA.u.y = cvtpk_bf16(p2, p3);
      pkA.u.z = cvtpk_bf16(p4, p5);   pkA.u.w = cvtpk_bf16(p6, p7);
      pkB.u.x = cvtpk_bf16(p8, p9);   pkB.u.y = cvtpk_bf16(pa_, pb_);
      pkB.u.z = cvtpk_bf16(pc_, pd_); pkB.u.w = cvtpk_bf16(pe_, pf_);
      oa0A = __builtin_amdgcn_mfma_f32_16x16x32_bf16(pkA.s, cv0, oa0A, 0, 0, 0);
      oa1A = __builtin_amdgcn_mfma_f32_16x16x32_bf16(pkA.s, cv1, oa1A, 0, 0, 0);
      oLA  = __builtin_amdgcn_mfma_f32_16x16x32_bf16(pkA.s, onesB, oLA, 0, 0, 0);
      oa0A = __builtin_amdgcn_mfma_f32_16x16x32_bf16(pkB.s, cv2, oa0A, 0, 0, 0);
      oa1A = __builtin_amdgcn_mfma_f32_16x16x32_bf16(pkB.s, cv3, oa1A, 0, 0, 0);
      oLA  = __builtin_amdgcn_mfma_f32_16x16x32_bf16(pkB.s, onesB, oLA, 0, 0, 0);
    }
    // ---- q-tile B ----
    {
      f32x4 s0 = __builtin_amdgcn_mfma_f32_16x16x32_bf16(ck0, qfB, z, 0, 0, 0);
      f32x4 s1 = __builtin_amdgcn_mfma_f32_16x16x32_bf16(ck1, qfB, z, 0, 0, 0);
      f32x4 s2 = __builtin_amdgcn_mfma_f32_16x16x32_bf16(ck2, qfB, z, 0, 0, 0);
      f32x4 s3 = __builtin_amdgcn_mfma_f32_16x16x32_bf16(ck3, qfB, z, 0, 0, 0);
      float p0 = fexp2(s0.x), p1 = fexp2(s0.y), p2 = fexp2(s0.z), p3 = fexp2(s0.w);
      float p4 = fexp2(s1.x), p5 = fexp2(s1.y), p6 = fexp2(s1.z), p7 = fexp2(s1.w);
      float p8 = fexp2(s2.x), p9 = fexp2(s2.y), pa_ = fexp2(s2.z), pb_ = fexp2(s2.w);
      float pc_ = fexp2(s3.x), pd_ = fexp2(s3.y), pe_ = fexp2(s3.z), pf_ = fexp2(s3.w);
      union { u32x4 u; s16x8 s; } pkA, pkB;
      pkA.u.x = cvtpk_bf16(p0, p1);   pkA.u.y = cvtpk_bf16(p2, p3);
      pkA.u.z = cvtpk_bf16(p4, p5);   pkA.u.w = cvtpk_bf16(p6, p7);
      pkB.u.x = cvtpk_bf16(p8, p9);   pkB.u.y = cvtpk_bf16(pa_, pb_);
      pkB.u.z = cvtpk_bf16(pc_, pd_); pkB.u.w = cvtpk_bf16(pe_, pf_);
      oa0B = __builtin_amdgcn_mfma_f32_16x16x32_bf16(pkA.s, cv0, oa0B, 0, 0, 0);
      oa1B = __builtin_amdgcn_mfma_f32_16x16x32_bf16(pkA.s, cv1, oa1B, 0, 0, 0);
      oLB  = __builtin_amdgcn_mfma_f32_16x16x32_bf16(pkA.s, onesB, oLB, 0, 0, 0);
      oa0B = __builtin_amdgcn_mfma_f32_16x16x32_bf16(pkB.s, cv2, oa0B, 0, 0, 0);
      oa1B = __builtin_amdgcn_mfma_f32_16x16x32_bf16(pkB.s, cv3, oa1B, 0, 0, 0);
      oLB  = __builtin_amdgcn_mfma_f32_16x16x32_bf16(pkB.s, onesB, oLB, 0, 0, 0);
    }

    __syncthreads();                 // all reads of Kl/Vl done
    *(s16x8*)(kdst) = kr;            // overwrite with next tile
    *(s16x8*)(vdst) = vr;
    __syncthreads();                 // next tile visible
  }

  // partial store: Opart[ch][b][h][q][d], Lpart[ch][b][h][q]
  const int bh = b * NH_ + h;
  float* opb = Opart + ((size_t)ch * (B_ * NH_) + bh) * ((size_t)N_ * HD_);
  #pragma unroll
  for (int r = 0; r < 4; ++r) {
    const int qrow = q0 + g*4 + r;
    opb[(size_t)qrow * HD_ + lq]             = oa0A[r];
    opb[(size_t)qrow * HD_ + lq + 16]        = oa1A[r];
    opb[(size_t)(qrow + 64) * HD_ + lq]      = oa0B[r];
    opb[(size_t)(qrow + 64) * HD_ + lq + 16] = oa1B[r];
  }
  if (lq == 0) {
    float* lp = Lpart + ((size_t)ch * (B_ * NH_) + bh) * N_ + q0 + g*4;
    lp[0] = oLA[0]; lp[1] = oLA[1]; lp[2] = oLA[2]; lp[3] = oLA[3];
    lp[64] = oLB[0]; lp[65] = oLB[1]; lp[66] = oLB[2]; lp[67] = oLB[3];
  }
}

// ---------------- Combine partials: sum chunks, normalize, transpose, bf16 out
__global__ __launch_bounds__(256) void k_comb(
    const float* __restrict__ Opart, const float* __restrict__ Lpart,
    u16* __restrict__ O) {
  __shared__ float T[32][65];
  __shared__ float linv[64];
  const int t = threadIdx.x;
  const int nt = blockIdx.x & 63, bh = blockIdx.x >> 6;
  const int n0 = nt * 64;
  const float* opb = Opart + (size_t)bh * ((size_t)N_ * HD_) + (size_t)n0 * HD_;

  f32x4 acc0 = {0.f,0.f,0.f,0.f}, acc1 = acc0;
  #pragma unroll
  for (int c = 0; c < NCH_; ++c) {
    const float* p = opb + (size_t)c * ((size_t)B_ * NH_ * N_ * HD_);
    acc0 += *(const f32x4*)(p + (size_t)t * 4);
    acc1 += *(const f32x4*)(p + (size_t)(t + 256) * 4);
  }
  if (t < 64) {
    float s = 0.f;
    #pragma unroll
    for (int c = 0; c < NCH_; ++c)
      s += Lpart[((size_t)c * (B_ * NH_) + bh) * N_ + n0 + t];
    linv[t] = 1.0f / s;
  }
  __syncthreads();
  {
    int nl = t >> 3, d0 = (t & 7) * 4;
    float iv = linv[nl];
    T[d0][nl] = acc0.x*iv; T[d0+1][nl] = acc0.y*iv;
    T[d0+2][nl] = acc0.z*iv; T[d0+3][nl] = acc0.w*iv;
    nl = (t + 256) >> 3; d0 = (t & 7) * 4;
    iv = linv[nl];
    T[d0][nl] = acc1.x*iv; T[d0+1][nl] = acc1.y*iv;
    T[d0+2][nl] = acc1.z*iv; T[d0+3][nl] = acc1.w*iv;
  }
  __syncthreads();
  u16* ob = O + (size_t)bh * (HD_ * N_) + n0;   // O[b][h*32+d][n] bf16
  const int row = t >> 3, col = (t & 7) * 8;
  u32x4 pk = { cvtpk_bf16(T[row][col],   T[row][col+1]),
               cvtpk_bf16(T[row][col+2], T[row][col+3]),
               cvtpk_bf16(T[row][col+4], T[row][col+5]),
               cvtpk_bf16(T[row][col+6], T[row][col+7]) };
  *(u32x4*)(ob + (size_t)row * N_ + col) = pk;
}

// ---------------- Out GEMM + bias + residual (O bf16 in, y f32 out) ----------
// Grid (8, 32, B): n-block 512, o-block 4 -> 512 blocks (2/CU).
__global__ __launch_bounds__(256) void k_gemm_out(
    const u16* __restrict__ O, const float* __restrict__ w,
    const float* __restrict__ bias, const float* __restrict__ x,
    float* __restrict__ y) {
  const int tid = threadIdx.x;
  const int n0 = blockIdx.x * 512 + tid * 2;
  const int o0 = blockIdx.y * 4;
  const int b  = blockIdx.z;
  const u16* ob = O + (size_t)b * C_ * N_;
  const float* wp = w + (size_t)o0 * C_;
  float ax[4] = {0,0,0,0};
  float ay[4] = {0,0,0,0};
  #pragma unroll 4
  for (int c = 0; c < C_; ++c) {
    const u32 wv = *(const u32*)(ob + (size_t)c * N_ + n0);
    const float x0 = bflo(wv), x1 = bfhi(wv);
    #pragma unroll
    for (int i = 0; i < 4; ++i) {
      const float wi = wp[(size_t)i * C_ + c];
      ax[i] += x0 * wi;
      ay[i] += x1 * wi;
    }
  }
  const size_t yo = ((size_t)b * C_ + o0) * N_ + n0;
  #pragma unroll
  for (int i = 0; i < 4; ++i) {
    const f32x2 xr = *(const f32x2*)(x + yo + (size_t)i * N_);
    f32x2 r = { ax[i] + bias[o0+i] + xr.x, ay[i] + bias[o0+i] + xr.y };
    *(f32x2*)(y + yo + (size_t)i * N_) = r;
  }
}

extern "C" void kernel_launch(void* const* d_in, const int* in_sizes, int n_in,
                              void* d_out, int out_size, void* d_ws, size_t ws_size,
                              hipStream_t stream) {
  const float* x     = (const float*)d_in[0];
  const float* gn_w  = (const float*)d_in[1];
  const float* gn_b  = (const float*)d_in[2];
  const float* qkv_w = (const float*)d_in[3];
  const float* qkv_b = (const float*)d_in[4];
  const float* out_w = (const float*)d_in[5];
  const float* out_b = (const float*)d_in[6];
  float* y = (float*)d_out;

  // ws layout (float offsets):
  //   xn    bf16: [0, 524288)            2 MB
  //   qkvb  bf16: [524288, 2097152)      6 MB  (Q scaled | unused | V); O aliases after attn
  //   Kt    bf16: [2097152, 2621440)     2 MB
  //   Opart f32 : [2621440, 6815744)    16 MB  (4 chunks x [b][h][4096][32])
  //   Lpart f32 : [6815744, 6946816)   0.5 MB
  float* ws  = (float*)d_ws;
  u16*   xn   = (u16*)ws;
  u16*   qkvb = (u16*)(ws + 524288);
  u16*   Kt   = (u16*)(ws + 2097152);
  float* Opart = ws + 2621440;
  float* Lpart = ws + 6815744;
  u16*   O    = qkvb;                    // alias (qkvb dead after k_attn)

  k_groupnorm<<<dim3(B_ * GROUPS_), 256, 0, stream>>>(x, gn_w, gn_b, xn);
  k_gemm_qkv <<<dim3(8, 48, B_),    256, 0, stream>>>(xn, qkv_w, qkv_b, qkvb, Kt);
  k_attn     <<<dim3(32 * NCH_, NH_, B_), 256, 0, stream>>>(qkvb, Kt, Opart, Lpart);
  k_comb     <<<dim3(512),          256, 0, stream>>>(Opart, Lpart, O);
  k_gemm_out <<<dim3(8, 32, B_),    256, 0, stream>>>(O, out_w, out_b, x, y);
}

// Round 14
// 75.785 us; speedup vs baseline: 1.2117x; 1.0530x over previous
//
#include <hip/hip_runtime.h>
#include <hip/hip_bf16.h>

#define B_ 2
#define C_ 128
#define N_ 4096
#define NH_ 4
#define HD_ 32
#define GROUPS_ 32
#define EPS_ 1e-5f
// (1/sqrt(32)) * log2(e): QK^T computed directly in log2 domain
#define SCALE2_ 0.25503486f
#define NCH_ 4           // KV chunks
#define CHKV_ 1024       // KV rows per chunk
#define NT_ (CHKV_ / 64) // 64-row KV tiles per chunk

typedef __attribute__((ext_vector_type(2))) float f32x2;
typedef __attribute__((ext_vector_type(4))) float f32x4;
typedef __attribute__((ext_vector_type(8))) short s16x8;
typedef __attribute__((ext_vector_type(2))) unsigned int u32x2;
typedef __attribute__((ext_vector_type(4))) unsigned int u32x4;
typedef unsigned short u16;
typedef unsigned int u32;

static __device__ __forceinline__ u32 cvtpk_bf16(float lo, float hi) {
  u32 r;
  asm("v_cvt_pk_bf16_f32 %0, %1, %2" : "=v"(r) : "v"(lo), "v"(hi));
  return r;
}
// raw v_exp_f32: inputs bounded (|S*log2e| < ~12), no denorm fixup needed
static __device__ __forceinline__ float fexp2(float x) {
  float r;
  asm("v_exp_f32 %0, %1" : "=v"(r) : "v"(x));
  return r;
}
// unpack u32 holding 2 bf16 -> 2 f32 (low halfword = first element)
static __device__ __forceinline__ float bflo(u32 w) { return __uint_as_float(w << 16); }
static __device__ __forceinline__ float bfhi(u32 w) { return __uint_as_float(w & 0xffff0000u); }

// ---------------- GroupNorm -> bf16 xn. One block per (b, group) -------------
__global__ __launch_bounds__(256) void k_groupnorm(
    const float* __restrict__ x, const float* __restrict__ gw,
    const float* __restrict__ gb, u16* __restrict__ xn) {
  const int blk = blockIdx.x;            // b*GROUPS + g
  const int tid = threadIdx.x;
  const size_t base = (size_t)blk * (4 * N_);   // contiguous 16384 elems
  const f32x4* x4 = (const f32x4*)(x + base);
  float s = 0.f, ss = 0.f;
  for (int i = tid; i < 4096; i += 256) {
    f32x4 v = x4[i];
    s  += v.x + v.y + v.z + v.w;
    ss += v.x*v.x + v.y*v.y + v.z*v.z + v.w*v.w;
  }
  for (int off = 32; off; off >>= 1) {
    s  += __shfl_down(s, off);
    ss += __shfl_down(ss, off);
  }
  __shared__ float red[2][4];
  __shared__ float mv[2];
  const int wid = tid >> 6;
  if ((tid & 63) == 0) { red[0][wid] = s; red[1][wid] = ss; }
  __syncthreads();
  if (tid == 0) {
    float S = red[0][0]+red[0][1]+red[0][2]+red[0][3];
    float Q = red[1][0]+red[1][1]+red[1][2]+red[1][3];
    float mu  = S * (1.f/16384.f);
    float var = Q * (1.f/16384.f) - mu*mu;
    mv[0] = mu; mv[1] = rsqrtf(var + EPS_);
  }
  __syncthreads();
  const float mu = mv[0], rs = mv[1];
  const int gi = blk & (GROUPS_ - 1);
  u32x2* xn2 = (u32x2*)(xn + base);
  for (int i = tid; i < 4096; i += 256) {
    const int c = gi*4 + (i >> 10);
    const float a  = gw[c] * rs;
    const float b2 = gb[c] - mu * a;
    f32x4 v = x4[i];
    f32x4 r = v * a + b2;
    u32x2 p = { cvtpk_bf16(r.x, r.y), cvtpk_bf16(r.z, r.w) };
    xn2[i] = p;
  }
}

// ---------------- QKV GEMM -> bf16; K rows written TRANSPOSED to Kt ----------
// Grid (8, 48, B): n-block 512, o-block 8 -> 768 blocks (3/CU, balanced).
// o0<128: Q*(SCALE2_) -> qkvb rows. o0 in [128,256): -> Kt[b][h][m][d] only.
// o0>=256: V -> qkvb rows.
__global__ __launch_bounds__(256) void k_gemm_qkv(
    const u16* __restrict__ xn, const float* __restrict__ w,
    const float* __restrict__ bias, u16* __restrict__ qkvb,
    u16* __restrict__ Kt) {
  const int tid = threadIdx.x;
  const int n0 = blockIdx.x * 512 + tid * 2;
  const int o0 = blockIdx.y * 8;
  const int b  = blockIdx.z;
  const u16* xb = xn + (size_t)b * C_ * N_;
  const float* wp = w + (size_t)o0 * C_;
  float ax[8] = {0,0,0,0,0,0,0,0};
  float ay[8] = {0,0,0,0,0,0,0,0};
  #pragma unroll 4
  for (int c = 0; c < C_; ++c) {
    const u32 wv = *(const u32*)(xb + (size_t)c * N_ + n0);
    const float x0 = bflo(wv), x1 = bfhi(wv);
    #pragma unroll
    for (int i = 0; i < 8; ++i) {
      const float wi = wp[(size_t)i * C_ + c];
      ax[i] += x0 * wi;
      ay[i] += x1 * wi;
    }
  }
  #pragma unroll
  for (int i = 0; i < 8; ++i) {
    const float bi = bias[o0 + i];
    ax[i] += bi; ay[i] += bi;
  }
  if (o0 < 128) {            // Q: scale and write rows
    u16* op = qkvb + ((size_t)b * 384 + o0) * N_ + n0;
    #pragma unroll
    for (int i = 0; i < 8; ++i)
      *(u32*)(op + (size_t)i * N_) = cvtpk_bf16(ax[i] * SCALE2_, ay[i] * SCALE2_);
  } else if (o0 < 256) {     // K: transposed into Kt[b][h][m][d]
    const int h  = (o0 - 128) >> 5;
    const int d8 = (o0 - 128) & 31;
    u16* kb = Kt + (size_t)(b * NH_ + h) * N_ * HD_ + d8;
    u32x4 pk0 = { cvtpk_bf16(ax[0], ax[1]), cvtpk_bf16(ax[2], ax[3]),
                  cvtpk_bf16(ax[4], ax[5]), cvtpk_bf16(ax[6], ax[7]) };
    u32x4 pk1 = { cvtpk_bf16(ay[0], ay[1]), cvtpk_bf16(ay[2], ay[3]),
                  cvtpk_bf16(ay[4], ay[5]), cvtpk_bf16(ay[6], ay[7]) };
    *(u32x4*)(kb + (size_t)n0 * HD_)       = pk0;
    *(u32x4*)(kb + (size_t)(n0 + 1) * HD_) = pk1;
  } else {                   // V: write rows
    u16* op = qkvb + ((size_t)b * 384 + o0) * N_ + n0;
    #pragma unroll
    for (int i = 0; i < 8; ++i)
      *(u32*)(op + (size_t)i * N_) = cvtpk_bf16(ax[i], ay[i]);
  }
}

// ---------------- Flash attention: EXACT R11/R13 version (passed @79.8us) ----
// 2 q-tiles/wave, single LDS buffer, two barriers/tile, no min-waves bound.
__global__ __launch_bounds__(256) void k_attn(
    const u16* __restrict__ qkvb, const u16* __restrict__ Kt,
    float* __restrict__ Opart, float* __restrict__ Lpart) {
  __shared__ u16 Kl[64 * 32];      // [m][d] 4KB, 16B-slot swizzled
  __shared__ u16 Vl[32 * 72];      // [d][m padded] 4.5KB
  const int b = blockIdx.z, h = blockIdx.y;
  const int qt = blockIdx.x & 31, ch = blockIdx.x >> 5;
  const int tid = threadIdx.x;
  const int wid = tid >> 6, lane = tid & 63;
  const int g = lane >> 4, lq = lane & 15;
  const int q0 = qt * 128 + wid * 16;        // second tile at q0+64
  const int kv0 = ch * CHKV_;

  // Q B-frags (bf16, pre-scaled): one-time scattered u16 loads
  const u16* qb = qkvb + ((size_t)b * 384 + h * HD_) * N_;
  s16x8 qfA, qfB;
  #pragma unroll
  for (int j = 0; j < 8; ++j) {
    qfA[j] = (short)qb[(size_t)(8*g + j) * N_ + q0 + lq];
    qfB[j] = (short)qb[(size_t)(8*g + j) * N_ + q0 + 64 + lq];
  }

  const u16* ktb = Kt + (size_t)(b * NH_ + h) * N_ * HD_;            // [m][d]
  const u16* vbb = qkvb + ((size_t)b * 384 + 256 + h * HD_) * N_;    // [d][m]
  const int pi = ((lq >> 2) << 3) + (lq & 3);   // A-row -> K row permutation

  // staging (coalesced): K = one s16x8/thread, V = one s16x8/thread
  const u16* kst = ktb + (size_t)kv0 * HD_ + tid * 8;        // + tt*64*HD_
  const int vrow = tid >> 3;            // 0..31 (d)
  const int vcol = (tid & 7) * 8;       // 0..56 (m)
  const u16* vst = vbb + (size_t)vrow * N_ + kv0 + vcol;     // + tt*64
  u16* kdst = Kl + ((tid * 8) ^ (((tid >> 5) & 3) * 8));     // swizzled slot
  u16* vdst = Vl + vrow * 72 + vcol;

  // fragment LDS addresses (elements); K slots swizzled by x=(pi>>3)&3
  const int xsw  = (pi >> 3) & 3;
  const int slot = 8 * (g ^ xsw);
  const int ka0 = (pi)      * 32 + slot;
  const int ka1 = (pi + 4)  * 32 + slot;
  const int ka2 = (pi + 32) * 32 + slot;
  const int ka3 = (pi + 36) * 32 + slot;
  const int va0 = lq * 72 + 8*g;
  const int va1 = (lq + 16) * 72 + 8*g;

  const short one_bf = (short)0x3F80;   // bf16 1.0
  const s16x8 onesB = {one_bf, one_bf, one_bf, one_bf,
                       one_bf, one_bf, one_bf, one_bf};

  f32x4 oa0A = {0.f,0.f,0.f,0.f}, oa1A = oa0A, oLA = oa0A;
  f32x4 oa0B = oa0A, oa1B = oa0A, oLB = oa0A;

  // prologue: stage tile 0
  {
    s16x8 kr = *(const s16x8*)(kst);
    s16x8 vr = *(const s16x8*)(vst);
    *(s16x8*)(kdst) = kr;
    *(s16x8*)(vdst) = vr;
  }
  __syncthreads();

  for (int tt = 0; tt < NT_; ++tt) {
    // issue next-tile loads early (clamped on last iter; rewrite is harmless)
    const int tn = (tt + 1 < NT_) ? (tt + 1) : (NT_ - 1);
    s16x8 kr = *(const s16x8*)(kst + (size_t)tn * 64 * HD_);
    s16x8 vr = *(const s16x8*)(vst + (size_t)tn * 64);

    // fragments from LDS (shared by both q-tiles)
    const s16x8 ck0 = *(const s16x8*)(Kl + ka0);
    const s16x8 ck1 = *(const s16x8*)(Kl + ka1);
    const s16x8 ck2 = *(const s16x8*)(Kl + ka2);
    const s16x8 ck3 = *(const s16x8*)(Kl + ka3);
    const s16x8 cv0 = *(const s16x8*)(Vl + va0);
    const s16x8 cv1 = *(const s16x8*)(Vl + va1);
    const s16x8 cv2 = *(const s16x8*)(Vl + va0 + 32);
    const s16x8 cv3 = *(const s16x8*)(Vl + va1 + 32);

    const f32x4 z = {0.f,0.f,0.f,0.f};
    // ---- q-tile A ----
    {
      f32x4 s0 = __builtin_amdgcn_mfma_f32_16x16x32_bf16(ck0, qfA, z, 0, 0, 0);
      f32x4 s1 = __builtin_amdgcn_mfma_f32_16x16x32_bf16(ck1, qfA, z, 0, 0, 0);
      f32x4 s2 = __builtin_amdgcn_mfma_f32_16x16x32_bf16(ck2, qfA, z, 0, 0, 0);
      f32x4 s3 = __builtin_amdgcn_mfma_f32_16x16x32_bf16(ck3, qfA, z, 0, 0, 0);
      float p0 = fexp2(s0.x), p1 = fexp2(s0.y), p2 = fexp2(s0.z), p3 = fexp2(s0.w);
      float p4 = fexp2(s1.x), p5 = fexp2(s1.y), p6 = fexp2(s1.z), p7 = fexp2(s1.w);
      float p8 = fexp2(s2.x), p9 = fexp2(s2.y), pa_ = fexp2(s2.z), pb_ = fexp2(s2.w);
      float pc_ = fexp2(s3.x), pd_ = fexp2(s3.y), pe_ = fexp2(s3.z), pf_ = fexp2(s3.w);
      union { u32x4 u; s16x8 s; } pkA, pkB;
      pkA.u.x = cvtpk_bf16(p0, p1);   pkA.u.y = cvtpk_bf16(p2, p3);
      pkA.u.z = cvtpk_bf16(p4, p5);   pkA.u.w = cvtpk_bf16(p6, p7);
      pkB.u.x = cvtpk_bf16(p8, p9);   pkB.u.y = cvtpk_bf16(pa_, pb_);
      pkB.u.z = cvtpk_bf16(pc_, pd_); pkB.u.w = cvtpk_bf16(pe_, pf_);
      oa0A = __builtin_amdgcn_mfma_f32_16x16x32_bf16(pkA.s, cv0, oa0A, 0, 0, 0);
      oa1A = __builtin_amdgcn_mfma_f32_16x16x32_bf16(pkA.s, cv1, oa1A, 0, 0, 0);
      oLA  = __builtin_amdgcn_mfma_f32_16x16x32_bf16(pkA.s, onesB, oLA, 0, 0, 0);
      oa0A = __builtin_amdgcn_mfma_f32_16x16x32_bf16(pkB.s, cv2, oa0A, 0, 0, 0);
      oa1A = __builtin_amdgcn_mfma_f32_16x16x32_bf16(pkB.s, cv3, oa1A, 0, 0, 0);
      oLA  = __builtin_amdgcn_mfma_f32_16x16x32_bf16(pkB.s, onesB, oLA, 0, 0, 0);
    }
    // ---- q-tile B ----
    {
      f32x4 s0 = __builtin_amdgcn_mfma_f32_16x16x32_bf16(ck0, qfB, z, 0, 0, 0);
      f32x4 s1 = __builtin_amdgcn_mfma_f32_16x16x32_bf16(ck1, qfB, z, 0, 0, 0);
      f32x4 s2 = __builtin_amdgcn_mfma_f32_16x16x32_bf16(ck2, qfB, z, 0, 0, 0);
      f32x4 s3 = __builtin_amdgcn_mfma_f32_16x16x32_bf16(ck3, qfB, z, 0, 0, 0);
      float p0 = fexp2(s0.x), p1 = fexp2(s0.y), p2 = fexp2(s0.z), p3 = fexp2(s0.w);
      float p4 = fexp2(s1.x), p5 = fexp2(s1.y), p6 = fexp2(s1.z), p7 = fexp2(s1.w);
      float p8 = fexp2(s2.x), p9 = fexp2(s2.y), pa_ = fexp2(s2.z), pb_ = fexp2(s2.w);
      float pc_ = fexp2(s3.x), pd_ = fexp2(s3.y), pe_ = fexp2(s3.z), pf_ = fexp2(s3.w);
      union { u32x4 u; s16x8 s; } pkA, pkB;
      pkA.u.x = cvtpk_bf16(p0, p1);   pkA.u.y = cvtpk_bf16(p2, p3);
      pkA.u.z = cvtpk_bf16(p4, p5);   pkA.u.w = cvtpk_bf16(p6, p7);
      pkB.u.x = cvtpk_bf16(p8, p9);   pkB.u.y = cvtpk_bf16(pa_, pb_);
      pkB.u.z = cvtpk_bf16(pc_, pd_); pkB.u.w = cvtpk_bf16(pe_, pf_);
      oa0B = __builtin_amdgcn_mfma_f32_16x16x32_bf16(pkA.s, cv0, oa0B, 0, 0, 0);
      oa1B = __builtin_amdgcn_mfma_f32_16x16x32_bf16(pkA.s, cv1, oa1B, 0, 0, 0);
      oLB  = __builtin_amdgcn_mfma_f32_16x16x32_bf16(pkA.s, onesB, oLB, 0, 0, 0);
      oa0B = __builtin_amdgcn_mfma_f32_16x16x32_bf16(pkB.s, cv2, oa0B, 0, 0, 0);
      oa1B = __builtin_amdgcn_mfma_f32_16x16x32_bf16(pkB.s, cv3, oa1B, 0, 0, 0);
      oLB  = __builtin_amdgcn_mfma_f32_16x16x32_bf16(pkB.s, onesB, oLB, 0, 0, 0);
    }

    __syncthreads();                 // all reads of Kl/Vl done
    *(s16x8*)(kdst) = kr;            // overwrite with next tile
    *(s16x8*)(vdst) = vr;
    __syncthreads();                 // next tile visible
  }

  // partial store: Opart[ch][b][h][q][d], Lpart[ch][b][h][q]
  const int bh = b * NH_ + h;
  float* opb = Opart + ((size_t)ch * (B_ * NH_) + bh) * ((size_t)N_ * HD_);
  #pragma unroll
  for (int r = 0; r < 4; ++r) {
    const int qrow = q0 + g*4 + r;
    opb[(size_t)qrow * HD_ + lq]             = oa0A[r];
    opb[(size_t)qrow * HD_ + lq + 16]        = oa1A[r];
    opb[(size_t)(qrow + 64) * HD_ + lq]      = oa0B[r];
    opb[(size_t)(qrow + 64) * HD_ + lq + 16] = oa1B[r];
  }
  if (lq == 0) {
    float* lp = Lpart + ((size_t)ch * (B_ * NH_) + bh) * N_ + q0 + g*4;
    lp[0] = oLA[0]; lp[1] = oLA[1]; lp[2] = oLA[2]; lp[3] = oLA[3];
    lp[64] = oLB[0]; lp[65] = oLB[1]; lp[66] = oLB[2]; lp[67] = oLB[3];
  }
}

// ---------------- Fused combine + out GEMM + bias + residual -----------------
// Grid (32, 8, B): block = [128 n] x [16 o]. Stage: sum Opart chunks, normalize
// by per-head l, transpose to Ot[c][n] bf16 in LDS. Then register GEMM.
__global__ __launch_bounds__(256) void k_out(
    const float* __restrict__ Opart, const float* __restrict__ Lpart,
    const float* __restrict__ w, const float* __restrict__ bias,
    const float* __restrict__ x, float* __restrict__ y) {
  __shared__ u16 Ot[128][136];     // [c][n] bf16, +8 pad
  __shared__ float linv[NH_][128];
  const int t = threadIdx.x;
  const int n0 = blockIdx.x * 128;
  const int o0 = blockIdx.y * 16;
  const int b  = blockIdx.z;

  // per-head denominators for this n-range
  if (t < 128) {
    #pragma unroll
    for (int h = 0; h < NH_; ++h) {
      float s = 0.f;
      #pragma unroll
      for (int c = 0; c < NCH_; ++c)
        s += Lpart[((size_t)c * (B_ * NH_) + b * NH_ + h) * N_ + n0 + t];
      linv[h][t] = 1.0f / s;
    }
  }
  __syncthreads();

  // stage Ot[c=32h+d][n] = (sum_ch Opart[ch][bh][n0+n][d]) * linv[h][n]
  {
    const int dd = (t & 7) * 4;           // 0..28
    const int nb = t >> 3;                // 0..31
    #pragma unroll
    for (int h = 0; h < NH_; ++h) {
      const float* ob = Opart + (size_t)(b * NH_ + h) * ((size_t)N_ * HD_)
                      + (size_t)n0 * HD_ + dd;
      #pragma unroll
      for (int p = 0; p < 4; ++p) {
        const int nn = p * 32 + nb;
        f32x4 a = {0.f,0.f,0.f,0.f};
        #pragma unroll
        for (int c = 0; c < NCH_; ++c)
          a += *(const f32x4*)(ob + (size_t)c * ((size_t)B_ * NH_ * N_ * HD_)
                                  + (size_t)nn * HD_);
        const float iv = linv[h][nn];
        a *= iv;
        Ot[32*h + dd + 0][nn] = (u16)cvtpk_bf16(a.x, a.x);
        Ot[32*h + dd + 1][nn] = (u16)cvtpk_bf16(a.y, a.y);
        Ot[32*h + dd + 2][nn] = (u16)cvtpk_bf16(a.z, a.z);
        Ot[32*h + dd + 3][nn] = (u16)cvtpk_bf16(a.w, a.w);
      }
    }
  }
  __syncthreads();

  // GEMM: thread -> 2 o-rows x 4 n-cols
  const int n4  = (t & 31) * 4;             // 0..124
  const int orow = o0 + (t >> 5) * 2;       // 2 rows
  const float* w0p = w + (size_t)orow * C_;
  const float* w1p = w0p + C_;
  f32x4 acc0 = {0.f,0.f,0.f,0.f}, acc1 = acc0;
  #pragma unroll 4
  for (int c = 0; c < C_; ++c) {
    const u32x2 ov = *(const u32x2*)(&Ot[c][n4]);
    const f32x4 xv = { bflo(ov.x), bfhi(ov.x), bflo(ov.y), bfhi(ov.y) };
    acc0 += xv * w0p[c];
    acc1 += xv * w1p[c];
  }
  const size_t yo = ((size_t)b * C_ + orow) * N_ + n0 + n4;
  const f32x4 xr0 = *(const f32x4*)(x + yo);
  const f32x4 xr1 = *(const f32x4*)(x + yo + N_);
  *(f32x4*)(y + yo)      = acc0 + bias[orow]     + xr0;
  *(f32x4*)(y + yo + N_) = acc1 + bias[orow + 1] + xr1;
}

extern "C" void kernel_launch(void* const* d_in, const int* in_sizes, int n_in,
                              void* d_out, int out_size, void* d_ws, size_t ws_size,
                              hipStream_t stream) {
  const float* x     = (const float*)d_in[0];
  const float* gn_w  = (const float*)d_in[1];
  const float* gn_b  = (const float*)d_in[2];
  const float* qkv_w = (const float*)d_in[3];
  const float* qkv_b = (const float*)d_in[4];
  const float* out_w = (const float*)d_in[5];
  const float* out_b = (const float*)d_in[6];
  float* y = (float*)d_out;

  // ws layout (float offsets):
  //   xn    bf16: [0, 524288)            2 MB
  //   qkvb  bf16: [524288, 2097152)      6 MB  (Q scaled | unused | V)
  //   Kt    bf16: [2097152, 2621440)     2 MB
  //   Opart f32 : [2621440, 6815744)    16 MB  (4 chunks x [b][h][4096][32])
  //   Lpart f32 : [6815744, 6946816)   0.5 MB
  float* ws  = (float*)d_ws;
  u16*   xn   = (u16*)ws;
  u16*   qkvb = (u16*)(ws + 524288);
  u16*   Kt   = (u16*)(ws + 2097152);
  float* Opart = ws + 2621440;
  float* Lpart = ws + 6815744;

  k_groupnorm<<<dim3(B_ * GROUPS_), 256, 0, stream>>>(x, gn_w, gn_b, xn);
  k_gemm_qkv <<<dim3(8, 48, B_),    256, 0, stream>>>(xn, qkv_w, qkv_b, qkvb, Kt);
  k_attn     <<<dim3(32 * NCH_, NH_, B_), 256, 0, stream>>>(qkvb, Kt, Opart, Lpart);
  k_out      <<<dim3(32, 8, B_),    256, 0, stream>>>(Opart, Lpart, out_w, out_b, x, y);
}

// Round 15
// 75.416 us; speedup vs baseline: 1.2177x; 1.0049x over previous
//
#include <hip/hip_runtime.h>
#include <hip/hip_bf16.h>

#define B_ 2
#define C_ 128
#define N_ 4096
#define NH_ 4
#define HD_ 32
#define GROUPS_ 32
#define EPS_ 1e-5f
// (1/sqrt(32)) * log2(e): QK^T computed directly in log2 domain
#define SCALE2_ 0.25503486f
#define NCH_ 4           // KV chunks
#define CHKV_ 1024       // KV rows per chunk
#define NT_ (CHKV_ / 64) // 64-row KV tiles per chunk

typedef __attribute__((ext_vector_type(2))) float f32x2;
typedef __attribute__((ext_vector_type(4))) float f32x4;
typedef __attribute__((ext_vector_type(8))) short s16x8;
typedef __attribute__((ext_vector_type(2))) unsigned int u32x2;
typedef __attribute__((ext_vector_type(4))) unsigned int u32x4;
typedef unsigned short u16;
typedef unsigned int u32;

static __device__ __forceinline__ u32 cvtpk_bf16(float lo, float hi) {
  u32 r;
  asm("v_cvt_pk_bf16_f32 %0, %1, %2" : "=v"(r) : "v"(lo), "v"(hi));
  return r;
}
// raw v_exp_f32: inputs bounded (|S*log2e| < ~12), no denorm fixup needed
static __device__ __forceinline__ float fexp2(float x) {
  float r;
  asm("v_exp_f32 %0, %1" : "=v"(r) : "v"(x));
  return r;
}
// unpack u32 holding 2 bf16 -> 2 f32 (low halfword = first element)
static __device__ __forceinline__ float bflo(u32 w) { return __uint_as_float(w << 16); }
static __device__ __forceinline__ float bfhi(u32 w) { return __uint_as_float(w & 0xffff0000u); }

// ---------------- GroupNorm -> bf16 xn. One block per (b, group) -------------
__global__ __launch_bounds__(256) void k_groupnorm(
    const float* __restrict__ x, const float* __restrict__ gw,
    const float* __restrict__ gb, u16* __restrict__ xn) {
  const int blk = blockIdx.x;            // b*GROUPS + g
  const int tid = threadIdx.x;
  const size_t base = (size_t)blk * (4 * N_);   // contiguous 16384 elems
  const f32x4* x4 = (const f32x4*)(x + base);
  float s = 0.f, ss = 0.f;
  for (int i = tid; i < 4096; i += 256) {
    f32x4 v = x4[i];
    s  += v.x + v.y + v.z + v.w;
    ss += v.x*v.x + v.y*v.y + v.z*v.z + v.w*v.w;
  }
  for (int off = 32; off; off >>= 1) {
    s  += __shfl_down(s, off);
    ss += __shfl_down(ss, off);
  }
  __shared__ float red[2][4];
  __shared__ float mv[2];
  const int wid = tid >> 6;
  if ((tid & 63) == 0) { red[0][wid] = s; red[1][wid] = ss; }
  __syncthreads();
  if (tid == 0) {
    float S = red[0][0]+red[0][1]+red[0][2]+red[0][3];
    float Q = red[1][0]+red[1][1]+red[1][2]+red[1][3];
    float mu  = S * (1.f/16384.f);
    float var = Q * (1.f/16384.f) - mu*mu;
    mv[0] = mu; mv[1] = rsqrtf(var + EPS_);
  }
  __syncthreads();
  const float mu = mv[0], rs = mv[1];
  const int gi = blk & (GROUPS_ - 1);
  u32x2* xn2 = (u32x2*)(xn + base);
  for (int i = tid; i < 4096; i += 256) {
    const int c = gi*4 + (i >> 10);
    const float a  = gw[c] * rs;
    const float b2 = gb[c] - mu * a;
    f32x4 v = x4[i];
    f32x4 r = v * a + b2;
    u32x2 p = { cvtpk_bf16(r.x, r.y), cvtpk_bf16(r.z, r.w) };
    xn2[i] = p;
  }
}

// ---------------- QKV GEMM -> bf16; K rows written TRANSPOSED to Kt ----------
// Grid (8, 48, B): n-block 512, o-block 8 -> 768 blocks (3/CU, balanced).
// o0<128: Q*(SCALE2_) -> qkvb rows. o0 in [128,256): -> Kt[b][h][m][d] only.
// o0>=256: V -> qkvb rows.
__global__ __launch_bounds__(256) void k_gemm_qkv(
    const u16* __restrict__ xn, const float* __restrict__ w,
    const float* __restrict__ bias, u16* __restrict__ qkvb,
    u16* __restrict__ Kt) {
  const int tid = threadIdx.x;
  const int n0 = blockIdx.x * 512 + tid * 2;
  const int o0 = blockIdx.y * 8;
  const int b  = blockIdx.z;
  const u16* xb = xn + (size_t)b * C_ * N_;
  const float* wp = w + (size_t)o0 * C_;
  float ax[8] = {0,0,0,0,0,0,0,0};
  float ay[8] = {0,0,0,0,0,0,0,0};
  #pragma unroll 4
  for (int c = 0; c < C_; ++c) {
    const u32 wv = *(const u32*)(xb + (size_t)c * N_ + n0);
    const float x0 = bflo(wv), x1 = bfhi(wv);
    #pragma unroll
    for (int i = 0; i < 8; ++i) {
      const float wi = wp[(size_t)i * C_ + c];
      ax[i] += x0 * wi;
      ay[i] += x1 * wi;
    }
  }
  #pragma unroll
  for (int i = 0; i < 8; ++i) {
    const float bi = bias[o0 + i];
    ax[i] += bi; ay[i] += bi;
  }
  if (o0 < 128) {            // Q: scale and write rows
    u16* op = qkvb + ((size_t)b * 384 + o0) * N_ + n0;
    #pragma unroll
    for (int i = 0; i < 8; ++i)
      *(u32*)(op + (size_t)i * N_) = cvtpk_bf16(ax[i] * SCALE2_, ay[i] * SCALE2_);
  } else if (o0 < 256) {     // K: transposed into Kt[b][h][m][d]
    const int h  = (o0 - 128) >> 5;
    const int d8 = (o0 - 128) & 31;
    u16* kb = Kt + (size_t)(b * NH_ + h) * N_ * HD_ + d8;
    u32x4 pk0 = { cvtpk_bf16(ax[0], ax[1]), cvtpk_bf16(ax[2], ax[3]),
                  cvtpk_bf16(ax[4], ax[5]), cvtpk_bf16(ax[6], ax[7]) };
    u32x4 pk1 = { cvtpk_bf16(ay[0], ay[1]), cvtpk_bf16(ay[2], ay[3]),
                  cvtpk_bf16(ay[4], ay[5]), cvtpk_bf16(ay[6], ay[7]) };
    *(u32x4*)(kb + (size_t)n0 * HD_)       = pk0;
    *(u32x4*)(kb + (size_t)(n0 + 1) * HD_) = pk1;
  } else {                   // V: write rows
    u16* op = qkvb + ((size_t)b * 384 + o0) * N_ + n0;
    #pragma unroll
    for (int i = 0; i < 8; ++i)
      *(u32*)(op + (size_t)i * N_) = cvtpk_bf16(ax[i], ay[i]);
  }
}

// ---------------- Flash attention: 4 q-tiles/wave, LDS-staged K/V ------------
// R14 analysis: exp is the fixed VALU floor (~6.6us); everything else in attn
// is LDS/stage/barrier overhead per q-output. 8 ds_reads + 2 stage writes +
// 2 barriers per tile-iter now feed FOUR 16-row q-tiles (q0,+64,+128,+192).
// Grid (16*NCH, NH, B) = 512 blocks (2/CU); ~130 VGPR, no min-waves bound.
// Single LDS buffer, two barriers (R12 dbuf taint). K slots XOR-swizzled.
#define QTILE_STEP(qf, oa0, oa1, oL)                                           \
  {                                                                            \
    f32x4 s0 = __builtin_amdgcn_mfma_f32_16x16x32_bf16(ck0, qf, z, 0, 0, 0);   \
    f32x4 s1 = __builtin_amdgcn_mfma_f32_16x16x32_bf16(ck1, qf, z, 0, 0, 0);   \
    f32x4 s2 = __builtin_amdgcn_mfma_f32_16x16x32_bf16(ck2, qf, z, 0, 0, 0);   \
    f32x4 s3 = __builtin_amdgcn_mfma_f32_16x16x32_bf16(ck3, qf, z, 0, 0, 0);   \
    float p0 = fexp2(s0.x), p1 = fexp2(s0.y), p2 = fexp2(s0.z), p3 = fexp2(s0.w); \
    float p4 = fexp2(s1.x), p5 = fexp2(s1.y), p6 = fexp2(s1.z), p7 = fexp2(s1.w); \
    float p8 = fexp2(s2.x), p9 = fexp2(s2.y), pa_ = fexp2(s2.z), pb_ = fexp2(s2.w); \
    float pc_ = fexp2(s3.x), pd_ = fexp2(s3.y), pe_ = fexp2(s3.z), pf_ = fexp2(s3.w); \
    union { u32x4 u; s16x8 s; } pkA, pkB;                                      \
    pkA.u.x = cvtpk_bf16(p0, p1);   pkA.u.y = cvtpk_bf16(p2, p3);              \
    pkA.u.z = cvtpk_bf16(p4, p5);   pkA.u.w = cvtpk_bf16(p6, p7);              \
    pkB.u.x = cvtpk_bf16(p8, p9);   pkB.u.y = cvtpk_bf16(pa_, pb_);            \
    pkB.u.z = cvtpk_bf16(pc_, pd_); pkB.u.w = cvtpk_bf16(pe_, pf_);            \
    oa0 = __builtin_amdgcn_mfma_f32_16x16x32_bf16(pkA.s, cv0, oa0, 0, 0, 0);   \
    oa1 = __builtin_amdgcn_mfma_f32_16x16x32_bf16(pkA.s, cv1, oa1, 0, 0, 0);   \
    oL  = __builtin_amdgcn_mfma_f32_16x16x32_bf16(pkA.s, onesB, oL, 0, 0, 0);  \
    oa0 = __builtin_amdgcn_mfma_f32_16x16x32_bf16(pkB.s, cv2, oa0, 0, 0, 0);   \
    oa1 = __builtin_amdgcn_mfma_f32_16x16x32_bf16(pkB.s, cv3, oa1, 0, 0, 0);   \
    oL  = __builtin_amdgcn_mfma_f32_16x16x32_bf16(pkB.s, onesB, oL, 0, 0, 0);  \
  }

__global__ __launch_bounds__(256) void k_attn(
    const u16* __restrict__ qkvb, const u16* __restrict__ Kt,
    float* __restrict__ Opart, float* __restrict__ Lpart) {
  __shared__ u16 Kl[64 * 32];      // [m][d] 4KB, 16B-slot swizzled
  __shared__ u16 Vl[32 * 72];      // [d][m padded] 4.5KB
  const int b = blockIdx.z, h = blockIdx.y;
  const int qt = blockIdx.x & 15, ch = blockIdx.x >> 4;
  const int tid = threadIdx.x;
  const int wid = tid >> 6, lane = tid & 63;
  const int g = lane >> 4, lq = lane & 15;
  const int q0 = qt * 256 + wid * 16;        // tiles at +0, +64, +128, +192
  const int kv0 = ch * CHKV_;

  // Q B-frags (bf16, pre-scaled): one-time scattered u16 loads
  const u16* qb = qkvb + ((size_t)b * 384 + h * HD_) * N_;
  s16x8 qfA, qfB, qfC, qfD;
  #pragma unroll
  for (int j = 0; j < 8; ++j) {
    const u16* qr = qb + (size_t)(8*g + j) * N_ + q0 + lq;
    qfA[j] = (short)qr[0];
    qfB[j] = (short)qr[64];
    qfC[j] = (short)qr[128];
    qfD[j] = (short)qr[192];
  }

  const u16* ktb = Kt + (size_t)(b * NH_ + h) * N_ * HD_;            // [m][d]
  const u16* vbb = qkvb + ((size_t)b * 384 + 256 + h * HD_) * N_;    // [d][m]
  const int pi = ((lq >> 2) << 3) + (lq & 3);   // A-row -> K row permutation

  // staging (coalesced): K = one s16x8/thread, V = one s16x8/thread
  const u16* kst = ktb + (size_t)kv0 * HD_ + tid * 8;        // + tt*64*HD_
  const int vrow = tid >> 3;            // 0..31 (d)
  const int vcol = (tid & 7) * 8;       // 0..56 (m)
  const u16* vst = vbb + (size_t)vrow * N_ + kv0 + vcol;     // + tt*64
  u16* kdst = Kl + ((tid * 8) ^ (((tid >> 5) & 3) * 8));     // swizzled slot
  u16* vdst = Vl + vrow * 72 + vcol;

  // fragment LDS addresses (elements); K slots swizzled by x=(pi>>3)&3
  const int xsw  = (pi >> 3) & 3;
  const int slot = 8 * (g ^ xsw);
  const int ka0 = (pi)      * 32 + slot;
  const int ka1 = (pi + 4)  * 32 + slot;
  const int ka2 = (pi + 32) * 32 + slot;
  const int ka3 = (pi + 36) * 32 + slot;
  const int va0 = lq * 72 + 8*g;
  const int va1 = (lq + 16) * 72 + 8*g;

  const short one_bf = (short)0x3F80;   // bf16 1.0
  const s16x8 onesB = {one_bf, one_bf, one_bf, one_bf,
                       one_bf, one_bf, one_bf, one_bf};

  f32x4 oa0A = {0.f,0.f,0.f,0.f}, oa1A = oa0A, oLA = oa0A;
  f32x4 oa0B = oa0A, oa1B = oa0A, oLB = oa0A;
  f32x4 oa0C = oa0A, oa1C = oa0A, oLC = oa0A;
  f32x4 oa0D = oa0A, oa1D = oa0A, oLD = oa0A;

  // prologue: stage tile 0
  {
    s16x8 kr = *(const s16x8*)(kst);
    s16x8 vr = *(const s16x8*)(vst);
    *(s16x8*)(kdst) = kr;
    *(s16x8*)(vdst) = vr;
  }
  __syncthreads();

  for (int tt = 0; tt < NT_; ++tt) {
    // issue next-tile loads early (clamped on last iter; rewrite is harmless)
    const int tn = (tt + 1 < NT_) ? (tt + 1) : (NT_ - 1);
    s16x8 kr = *(const s16x8*)(kst + (size_t)tn * 64 * HD_);
    s16x8 vr = *(const s16x8*)(vst + (size_t)tn * 64);

    // fragments from LDS (shared by all four q-tiles)
    const s16x8 ck0 = *(const s16x8*)(Kl + ka0);
    const s16x8 ck1 = *(const s16x8*)(Kl + ka1);
    const s16x8 ck2 = *(const s16x8*)(Kl + ka2);
    const s16x8 ck3 = *(const s16x8*)(Kl + ka3);
    const s16x8 cv0 = *(const s16x8*)(Vl + va0);
    const s16x8 cv1 = *(const s16x8*)(Vl + va1);
    const s16x8 cv2 = *(const s16x8*)(Vl + va0 + 32);
    const s16x8 cv3 = *(const s16x8*)(Vl + va1 + 32);

    const f32x4 z = {0.f,0.f,0.f,0.f};
    QTILE_STEP(qfA, oa0A, oa1A, oLA)
    QTILE_STEP(qfB, oa0B, oa1B, oLB)
    QTILE_STEP(qfC, oa0C, oa1C, oLC)
    QTILE_STEP(qfD, oa0D, oa1D, oLD)

    __syncthreads();                 // all reads of Kl/Vl done
    *(s16x8*)(kdst) = kr;            // overwrite with next tile
    *(s16x8*)(vdst) = vr;
    __syncthreads();                 // next tile visible
  }

  // partial store: Opart[ch][b][h][q][d], Lpart[ch][b][h][q]
  const int bh = b * NH_ + h;
  float* opb = Opart + ((size_t)ch * (B_ * NH_) + bh) * ((size_t)N_ * HD_);
  #pragma unroll
  for (int r = 0; r < 4; ++r) {
    const int qrow = q0 + g*4 + r;
    opb[(size_t)qrow * HD_ + lq]              = oa0A[r];
    opb[(size_t)qrow * HD_ + lq + 16]         = oa1A[r];
    opb[(size_t)(qrow + 64) * HD_ + lq]       = oa0B[r];
    opb[(size_t)(qrow + 64) * HD_ + lq + 16]  = oa1B[r];
    opb[(size_t)(qrow + 128) * HD_ + lq]      = oa0C[r];
    opb[(size_t)(qrow + 128) * HD_ + lq + 16] = oa1C[r];
    opb[(size_t)(qrow + 192) * HD_ + lq]      = oa0D[r];
    opb[(size_t)(qrow + 192) * HD_ + lq + 16] = oa1D[r];
  }
  if (lq == 0) {
    float* lp = Lpart + ((size_t)ch * (B_ * NH_) + bh) * N_ + q0 + g*4;
    lp[0]   = oLA[0]; lp[1]   = oLA[1]; lp[2]   = oLA[2]; lp[3]   = oLA[3];
    lp[64]  = oLB[0]; lp[65]  = oLB[1]; lp[66]  = oLB[2]; lp[67]  = oLB[3];
    lp[128] = oLC[0]; lp[129] = oLC[1]; lp[130] = oLC[2]; lp[131] = oLC[3];
    lp[192] = oLD[0]; lp[193] = oLD[1]; lp[194] = oLD[2]; lp[195] = oLD[3];
  }
}

// ---------------- Fused combine + out GEMM + bias + residual -----------------
// Grid (32, 8, B): block = [128 n] x [16 o]. Stage: sum Opart chunks, normalize
// by per-head l, transpose to Ot[c][n] bf16 in LDS. Then register GEMM.
__global__ __launch_bounds__(256) void k_out(
    const float* __restrict__ Opart, const float* __restrict__ Lpart,
    const float* __restrict__ w, const float* __restrict__ bias,
    const float* __restrict__ x, float* __restrict__ y) {
  __shared__ u16 Ot[128][136];     // [c][n] bf16, +8 pad
  __shared__ float linv[NH_][128];
  const int t = threadIdx.x;
  const int n0 = blockIdx.x * 128;
  const int o0 = blockIdx.y * 16;
  const int b  = blockIdx.z;

  // per-head denominators for this n-range
  if (t < 128) {
    #pragma unroll
    for (int h = 0; h < NH_; ++h) {
      float s = 0.f;
      #pragma unroll
      for (int c = 0; c < NCH_; ++c)
        s += Lpart[((size_t)c * (B_ * NH_) + b * NH_ + h) * N_ + n0 + t];
      linv[h][t] = 1.0f / s;
    }
  }
  __syncthreads();

  // stage Ot[c=32h+d][n] = (sum_ch Opart[ch][bh][n0+n][d]) * linv[h][n]
  {
    const int dd = (t & 7) * 4;           // 0..28
    const int nb = t >> 3;                // 0..31
    #pragma unroll
    for (int h = 0; h < NH_; ++h) {
      const float* ob = Opart + (size_t)(b * NH_ + h) * ((size_t)N_ * HD_)
                      + (size_t)n0 * HD_ + dd;
      #pragma unroll
      for (int p = 0; p < 4; ++p) {
        const int nn = p * 32 + nb;
        f32x4 a = {0.f,0.f,0.f,0.f};
        #pragma unroll
        for (int c = 0; c < NCH_; ++c)
          a += *(const f32x4*)(ob + (size_t)c * ((size_t)B_ * NH_ * N_ * HD_)
                                  + (size_t)nn * HD_);
        const float iv = linv[h][nn];
        a *= iv;
        Ot[32*h + dd + 0][nn] = (u16)cvtpk_bf16(a.x, a.x);
        Ot[32*h + dd + 1][nn] = (u16)cvtpk_bf16(a.y, a.y);
        Ot[32*h + dd + 2][nn] = (u16)cvtpk_bf16(a.z, a.z);
        Ot[32*h + dd + 3][nn] = (u16)cvtpk_bf16(a.w, a.w);
      }
    }
  }
  __syncthreads();

  // GEMM: thread -> 2 o-rows x 4 n-cols
  const int n4  = (t & 31) * 4;             // 0..124
  const int orow = o0 + (t >> 5) * 2;       // 2 rows
  const float* w0p = w + (size_t)orow * C_;
  const float* w1p = w0p + C_;
  f32x4 acc0 = {0.f,0.f,0.f,0.f}, acc1 = acc0;
  #pragma unroll 4
  for (int c = 0; c < C_; ++c) {
    const u32x2 ov = *(const u32x2*)(&Ot[c][n4]);
    const f32x4 xv = { bflo(ov.x), bfhi(ov.x), bflo(ov.y), bfhi(ov.y) };
    acc0 += xv * w0p[c];
    acc1 += xv * w1p[c];
  }
  const size_t yo = ((size_t)b * C_ + orow) * N_ + n0 + n4;
  const f32x4 xr0 = *(const f32x4*)(x + yo);
  const f32x4 xr1 = *(const f32x4*)(x + yo + N_);
  *(f32x4*)(y + yo)      = acc0 + bias[orow]     + xr0;
  *(f32x4*)(y + yo + N_) = acc1 + bias[orow + 1] + xr1;
}

extern "C" void kernel_launch(void* const* d_in, const int* in_sizes, int n_in,
                              void* d_out, int out_size, void* d_ws, size_t ws_size,
                              hipStream_t stream) {
  const float* x     = (const float*)d_in[0];
  const float* gn_w  = (const float*)d_in[1];
  const float* gn_b  = (const float*)d_in[2];
  const float* qkv_w = (const float*)d_in[3];
  const float* qkv_b = (const float*)d_in[4];
  const float* out_w = (const float*)d_in[5];
  const float* out_b = (const float*)d_in[6];
  float* y = (float*)d_out;

  // ws layout (float offsets):
  //   xn    bf16: [0, 524288)            2 MB
  //   qkvb  bf16: [524288, 2097152)      6 MB  (Q scaled | unused | V)
  //   Kt    bf16: [2097152, 2621440)     2 MB
  //   Opart f32 : [2621440, 6815744)    16 MB  (4 chunks x [b][h][4096][32])
  //   Lpart f32 : [6815744, 6946816)   0.5 MB
  float* ws  = (float*)d_ws;
  u16*   xn   = (u16*)ws;
  u16*   qkvb = (u16*)(ws + 524288);
  u16*   Kt   = (u16*)(ws + 2097152);
  float* Opart = ws + 2621440;
  float* Lpart = ws + 6815744;

  k_groupnorm<<<dim3(B_ * GROUPS_), 256, 0, stream>>>(x, gn_w, gn_b, xn);
  k_gemm_qkv <<<dim3(8, 48, B_),    256, 0, stream>>>(xn, qkv_w, qkv_b, qkvb, Kt);
  k_attn     <<<dim3(16 * NCH_, NH_, B_), 256, 0, stream>>>(qkvb, Kt, Opart, Lpart);
  k_out      <<<dim3(32, 8, B_),    256, 0, stream>>>(Opart, Lpart, out_w, out_b, x, y);
}

// Round 16
// 68.368 us; speedup vs baseline: 1.3432x; 1.1031x over previous
//
#include <hip/hip_runtime.h>
#include <hip/hip_bf16.h>

#define B_ 2
#define C_ 128
#define N_ 4096
#define NH_ 4
#define HD_ 32
#define GROUPS_ 32
#define EPS_ 1e-5f
// (1/sqrt(32)) * log2(e): QK^T computed directly in log2 domain
#define SCALE2_ 0.25503486f
#define NCH_ 4           // KV chunks
#define CHKV_ 1024       // KV rows per chunk
#define NT_ (CHKV_ / 64) // 64-row KV tiles per chunk

typedef __attribute__((ext_vector_type(2))) float f32x2;
typedef __attribute__((ext_vector_type(4))) float f32x4;
typedef __attribute__((ext_vector_type(8))) short s16x8;
typedef __attribute__((ext_vector_type(2))) unsigned int u32x2;
typedef __attribute__((ext_vector_type(4))) unsigned int u32x4;
typedef unsigned short u16;
typedef unsigned int u32;

static __device__ __forceinline__ u32 cvtpk_bf16(float lo, float hi) {
  u32 r;
  asm("v_cvt_pk_bf16_f32 %0, %1, %2" : "=v"(r) : "v"(lo), "v"(hi));
  return r;
}
// raw v_exp_f32: inputs bounded (|S*log2e| < ~12), no denorm fixup needed
static __device__ __forceinline__ float fexp2(float x) {
  float r;
  asm("v_exp_f32 %0, %1" : "=v"(r) : "v"(x));
  return r;
}
// unpack u32 holding 2 bf16 -> 2 f32 (low halfword = first element)
static __device__ __forceinline__ float bflo(u32 w) { return __uint_as_float(w << 16); }
static __device__ __forceinline__ float bfhi(u32 w) { return __uint_as_float(w & 0xffff0000u); }
static __device__ __forceinline__ u16 f2bf16(float f) { return (u16)cvtpk_bf16(f, f); }

// ---------------- GroupNorm -> bf16 xn. One 1024-thread block per (b, group) -
// R15 analysis: 64 blocks x 256thr left the 16MB HBM pull at ~1/4 concurrency.
// 16 waves/block quadruples outstanding loads on the same 64 CUs.
__global__ __launch_bounds__(1024) void k_groupnorm(
    const float* __restrict__ x, const float* __restrict__ gw,
    const float* __restrict__ gb, u16* __restrict__ xn) {
  const int blk = blockIdx.x;            // b*GROUPS + g
  const int tid = threadIdx.x;
  const size_t base = (size_t)blk * (4 * N_);   // contiguous 16384 elems
  const f32x4* x4 = (const f32x4*)(x + base);
  float s = 0.f, ss = 0.f;
  #pragma unroll
  for (int i = tid; i < 4096; i += 1024) {
    f32x4 v = x4[i];
    s  += v.x + v.y + v.z + v.w;
    ss += v.x*v.x + v.y*v.y + v.z*v.z + v.w*v.w;
  }
  for (int off = 32; off; off >>= 1) {
    s  += __shfl_down(s, off);
    ss += __shfl_down(ss, off);
  }
  __shared__ float red[2][16];
  __shared__ float mv[2];
  const int wid = tid >> 6;
  if ((tid & 63) == 0) { red[0][wid] = s; red[1][wid] = ss; }
  __syncthreads();
  if (tid == 0) {
    float S = 0.f, Q = 0.f;
    #pragma unroll
    for (int i = 0; i < 16; ++i) { S += red[0][i]; Q += red[1][i]; }
    float mu  = S * (1.f/16384.f);
    float var = Q * (1.f/16384.f) - mu*mu;
    mv[0] = mu; mv[1] = rsqrtf(var + EPS_);
  }
  __syncthreads();
  const float mu = mv[0], rs = mv[1];
  const int gi = blk & (GROUPS_ - 1);
  u32x2* xn2 = (u32x2*)(xn + base);
  #pragma unroll
  for (int i = tid; i < 4096; i += 1024) {
    const int c = gi*4 + (i >> 10);
    const float a  = gw[c] * rs;
    const float b2 = gb[c] - mu * a;
    f32x4 v = x4[i];
    f32x4 r = v * a + b2;
    u32x2 p = { cvtpk_bf16(r.x, r.y), cvtpk_bf16(r.z, r.w) };
    xn2[i] = p;
  }
}

// ---------------- QKV GEMM -> bf16; K rows written TRANSPOSED to Kt ----------
// Grid (8, 48, B): n-block 512, o-block 8 -> 768 blocks (3/CU, balanced).
__global__ __launch_bounds__(256) void k_gemm_qkv(
    const u16* __restrict__ xn, const float* __restrict__ w,
    const float* __restrict__ bias, u16* __restrict__ qkvb,
    u16* __restrict__ Kt) {
  const int tid = threadIdx.x;
  const int n0 = blockIdx.x * 512 + tid * 2;
  const int o0 = blockIdx.y * 8;
  const int b  = blockIdx.z;
  const u16* xb = xn + (size_t)b * C_ * N_;
  const float* wp = w + (size_t)o0 * C_;
  float ax[8] = {0,0,0,0,0,0,0,0};
  float ay[8] = {0,0,0,0,0,0,0,0};
  #pragma unroll 4
  for (int c = 0; c < C_; ++c) {
    const u32 wv = *(const u32*)(xb + (size_t)c * N_ + n0);
    const float x0 = bflo(wv), x1 = bfhi(wv);
    #pragma unroll
    for (int i = 0; i < 8; ++i) {
      const float wi = wp[(size_t)i * C_ + c];
      ax[i] += x0 * wi;
      ay[i] += x1 * wi;
    }
  }
  #pragma unroll
  for (int i = 0; i < 8; ++i) {
    const float bi = bias[o0 + i];
    ax[i] += bi; ay[i] += bi;
  }
  if (o0 < 128) {            // Q: scale and write rows
    u16* op = qkvb + ((size_t)b * 384 + o0) * N_ + n0;
    #pragma unroll
    for (int i = 0; i < 8; ++i)
      *(u32*)(op + (size_t)i * N_) = cvtpk_bf16(ax[i] * SCALE2_, ay[i] * SCALE2_);
  } else if (o0 < 256) {     // K: transposed into Kt[b][h][m][d]
    const int h  = (o0 - 128) >> 5;
    const int d8 = (o0 - 128) & 31;
    u16* kb = Kt + (size_t)(b * NH_ + h) * N_ * HD_ + d8;
    u32x4 pk0 = { cvtpk_bf16(ax[0], ax[1]), cvtpk_bf16(ax[2], ax[3]),
                  cvtpk_bf16(ax[4], ax[5]), cvtpk_bf16(ax[6], ax[7]) };
    u32x4 pk1 = { cvtpk_bf16(ay[0], ay[1]), cvtpk_bf16(ay[2], ay[3]),
                  cvtpk_bf16(ay[4], ay[5]), cvtpk_bf16(ay[6], ay[7]) };
    *(u32x4*)(kb + (size_t)n0 * HD_)       = pk0;
    *(u32x4*)(kb + (size_t)(n0 + 1) * HD_) = pk1;
  } else {                   // V: write rows
    u16* op = qkvb + ((size_t)b * 384 + o0) * N_ + n0;
    #pragma unroll
    for (int i = 0; i < 8; ++i)
      *(u32*)(op + (size_t)i * N_) = cvtpk_bf16(ax[i], ay[i]);
  }
}

// ---------------- Flash attention: 4 q-tiles/wave, LDS-staged K/V ------------
// Partials now stored BF16 (halves Opart traffic; error budget ~+0.005).
#define QTILE_STEP(qf, oa0, oa1, oL)                                           \
  {                                                                            \
    f32x4 s0 = __builtin_amdgcn_mfma_f32_16x16x32_bf16(ck0, qf, z, 0, 0, 0);   \
    f32x4 s1 = __builtin_amdgcn_mfma_f32_16x16x32_bf16(ck1, qf, z, 0, 0, 0);   \
    f32x4 s2 = __builtin_amdgcn_mfma_f32_16x16x32_bf16(ck2, qf, z, 0, 0, 0);   \
    f32x4 s3 = __builtin_amdgcn_mfma_f32_16x16x32_bf16(ck3, qf, z, 0, 0, 0);   \
    float p0 = fexp2(s0.x), p1 = fexp2(s0.y), p2 = fexp2(s0.z), p3 = fexp2(s0.w); \
    float p4 = fexp2(s1.x), p5 = fexp2(s1.y), p6 = fexp2(s1.z), p7 = fexp2(s1.w); \
    float p8 = fexp2(s2.x), p9 = fexp2(s2.y), pa_ = fexp2(s2.z), pb_ = fexp2(s2.w); \
    float pc_ = fexp2(s3.x), pd_ = fexp2(s3.y), pe_ = fexp2(s3.z), pf_ = fexp2(s3.w); \
    union { u32x4 u; s16x8 s; } pkA, pkB;                                      \
    pkA.u.x = cvtpk_bf16(p0, p1);   pkA.u.y = cvtpk_bf16(p2, p3);              \
    pkA.u.z = cvtpk_bf16(p4, p5);   pkA.u.w = cvtpk_bf16(p6, p7);              \
    pkB.u.x = cvtpk_bf16(p8, p9);   pkB.u.y = cvtpk_bf16(pa_, pb_);            \
    pkB.u.z = cvtpk_bf16(pc_, pd_); pkB.u.w = cvtpk_bf16(pe_, pf_);            \
    oa0 = __builtin_amdgcn_mfma_f32_16x16x32_bf16(pkA.s, cv0, oa0, 0, 0, 0);   \
    oa1 = __builtin_amdgcn_mfma_f32_16x16x32_bf16(pkA.s, cv1, oa1, 0, 0, 0);   \
    oL  = __builtin_amdgcn_mfma_f32_16x16x32_bf16(pkA.s, onesB, oL, 0, 0, 0);  \
    oa0 = __builtin_amdgcn_mfma_f32_16x16x32_bf16(pkB.s, cv2, oa0, 0, 0, 0);   \
    oa1 = __builtin_amdgcn_mfma_f32_16x16x32_bf16(pkB.s, cv3, oa1, 0, 0, 0);   \
    oL  = __builtin_amdgcn_mfma_f32_16x16x32_bf16(pkB.s, onesB, oL, 0, 0, 0);  \
  }

__global__ __launch_bounds__(256) void k_attn(
    const u16* __restrict__ qkvb, const u16* __restrict__ Kt,
    u16* __restrict__ Opart, float* __restrict__ Lpart) {
  __shared__ u16 Kl[64 * 32];      // [m][d] 4KB, 16B-slot swizzled
  __shared__ u16 Vl[32 * 72];      // [d][m padded] 4.5KB
  const int b = blockIdx.z, h = blockIdx.y;
  const int qt = blockIdx.x & 15, ch = blockIdx.x >> 4;
  const int tid = threadIdx.x;
  const int wid = tid >> 6, lane = tid & 63;
  const int g = lane >> 4, lq = lane & 15;
  const int q0 = qt * 256 + wid * 16;        // tiles at +0, +64, +128, +192
  const int kv0 = ch * CHKV_;

  // Q B-frags (bf16, pre-scaled): one-time scattered u16 loads
  const u16* qb = qkvb + ((size_t)b * 384 + h * HD_) * N_;
  s16x8 qfA, qfB, qfC, qfD;
  #pragma unroll
  for (int j = 0; j < 8; ++j) {
    const u16* qr = qb + (size_t)(8*g + j) * N_ + q0 + lq;
    qfA[j] = (short)qr[0];
    qfB[j] = (short)qr[64];
    qfC[j] = (short)qr[128];
    qfD[j] = (short)qr[192];
  }

  const u16* ktb = Kt + (size_t)(b * NH_ + h) * N_ * HD_;            // [m][d]
  const u16* vbb = qkvb + ((size_t)b * 384 + 256 + h * HD_) * N_;    // [d][m]
  const int pi = ((lq >> 2) << 3) + (lq & 3);   // A-row -> K row permutation

  // staging (coalesced): K = one s16x8/thread, V = one s16x8/thread
  const u16* kst = ktb + (size_t)kv0 * HD_ + tid * 8;        // + tt*64*HD_
  const int vrow = tid >> 3;            // 0..31 (d)
  const int vcol = (tid & 7) * 8;       // 0..56 (m)
  const u16* vst = vbb + (size_t)vrow * N_ + kv0 + vcol;     // + tt*64
  u16* kdst = Kl + ((tid * 8) ^ (((tid >> 5) & 3) * 8));     // swizzled slot
  u16* vdst = Vl + vrow * 72 + vcol;

  // fragment LDS addresses (elements); K slots swizzled by x=(pi>>3)&3
  const int xsw  = (pi >> 3) & 3;
  const int slot = 8 * (g ^ xsw);
  const int ka0 = (pi)      * 32 + slot;
  const int ka1 = (pi + 4)  * 32 + slot;
  const int ka2 = (pi + 32) * 32 + slot;
  const int ka3 = (pi + 36) * 32 + slot;
  const int va0 = lq * 72 + 8*g;
  const int va1 = (lq + 16) * 72 + 8*g;

  const short one_bf = (short)0x3F80;   // bf16 1.0
  const s16x8 onesB = {one_bf, one_bf, one_bf, one_bf,
                       one_bf, one_bf, one_bf, one_bf};

  f32x4 oa0A = {0.f,0.f,0.f,0.f}, oa1A = oa0A, oLA = oa0A;
  f32x4 oa0B = oa0A, oa1B = oa0A, oLB = oa0A;
  f32x4 oa0C = oa0A, oa1C = oa0A, oLC = oa0A;
  f32x4 oa0D = oa0A, oa1D = oa0A, oLD = oa0A;

  // prologue: stage tile 0
  {
    s16x8 kr = *(const s16x8*)(kst);
    s16x8 vr = *(const s16x8*)(vst);
    *(s16x8*)(kdst) = kr;
    *(s16x8*)(vdst) = vr;
  }
  __syncthreads();

  for (int tt = 0; tt < NT_; ++tt) {
    // issue next-tile loads early (clamped on last iter; rewrite is harmless)
    const int tn = (tt + 1 < NT_) ? (tt + 1) : (NT_ - 1);
    s16x8 kr = *(const s16x8*)(kst + (size_t)tn * 64 * HD_);
    s16x8 vr = *(const s16x8*)(vst + (size_t)tn * 64);

    // fragments from LDS (shared by all four q-tiles)
    const s16x8 ck0 = *(const s16x8*)(Kl + ka0);
    const s16x8 ck1 = *(const s16x8*)(Kl + ka1);
    const s16x8 ck2 = *(const s16x8*)(Kl + ka2);
    const s16x8 ck3 = *(const s16x8*)(Kl + ka3);
    const s16x8 cv0 = *(const s16x8*)(Vl + va0);
    const s16x8 cv1 = *(const s16x8*)(Vl + va1);
    const s16x8 cv2 = *(const s16x8*)(Vl + va0 + 32);
    const s16x8 cv3 = *(const s16x8*)(Vl + va1 + 32);

    const f32x4 z = {0.f,0.f,0.f,0.f};
    QTILE_STEP(qfA, oa0A, oa1A, oLA)
    QTILE_STEP(qfB, oa0B, oa1B, oLB)
    QTILE_STEP(qfC, oa0C, oa1C, oLC)
    QTILE_STEP(qfD, oa0D, oa1D, oLD)

    __syncthreads();                 // all reads of Kl/Vl done
    *(s16x8*)(kdst) = kr;            // overwrite with next tile
    *(s16x8*)(vdst) = vr;
    __syncthreads();                 // next tile visible
  }

  // partial store (bf16): Opart[ch][b][h][q][d], Lpart[ch][b][h][q]
  const int bh = b * NH_ + h;
  u16* opb = Opart + ((size_t)ch * (B_ * NH_) + bh) * ((size_t)N_ * HD_);
  #pragma unroll
  for (int r = 0; r < 4; ++r) {
    const int qrow = q0 + g*4 + r;
    opb[(size_t)qrow * HD_ + lq]              = f2bf16(oa0A[r]);
    opb[(size_t)qrow * HD_ + lq + 16]         = f2bf16(oa1A[r]);
    opb[(size_t)(qrow + 64) * HD_ + lq]       = f2bf16(oa0B[r]);
    opb[(size_t)(qrow + 64) * HD_ + lq + 16]  = f2bf16(oa1B[r]);
    opb[(size_t)(qrow + 128) * HD_ + lq]      = f2bf16(oa0C[r]);
    opb[(size_t)(qrow + 128) * HD_ + lq + 16] = f2bf16(oa1C[r]);
    opb[(size_t)(qrow + 192) * HD_ + lq]      = f2bf16(oa0D[r]);
    opb[(size_t)(qrow + 192) * HD_ + lq + 16] = f2bf16(oa1D[r]);
  }
  if (lq == 0) {
    float* lp = Lpart + ((size_t)ch * (B_ * NH_) + bh) * N_ + q0 + g*4;
    lp[0]   = oLA[0]; lp[1]   = oLA[1]; lp[2]   = oLA[2]; lp[3]   = oLA[3];
    lp[64]  = oLB[0]; lp[65]  = oLB[1]; lp[66]  = oLB[2]; lp[67]  = oLB[3];
    lp[128] = oLC[0]; lp[129] = oLC[1]; lp[130] = oLC[2]; lp[131] = oLC[3];
    lp[192] = oLD[0]; lp[193] = oLD[1]; lp[194] = oLD[2]; lp[195] = oLD[3];
  }
}

// ---------------- Fused combine + out GEMM + bias + residual -----------------
// Grid (32, 4, B): block = [128 n] x [32 o] (o-block widened: halves redundant
// Opart reads). Stage: sum bf16 Opart chunks, normalize, transpose to Ot.
__global__ __launch_bounds__(256) void k_out(
    const u16* __restrict__ Opart, const float* __restrict__ Lpart,
    const float* __restrict__ w, const float* __restrict__ bias,
    const float* __restrict__ x, float* __restrict__ y) {
  __shared__ u16 Ot[128][136];     // [c][n] bf16, +8 pad
  __shared__ float linv[NH_][128];
  const int t = threadIdx.x;
  const int n0 = blockIdx.x * 128;
  const int o0 = blockIdx.y * 32;
  const int b  = blockIdx.z;

  // per-head denominators for this n-range
  if (t < 128) {
    #pragma unroll
    for (int h = 0; h < NH_; ++h) {
      float s = 0.f;
      #pragma unroll
      for (int c = 0; c < NCH_; ++c)
        s += Lpart[((size_t)c * (B_ * NH_) + b * NH_ + h) * N_ + n0 + t];
      linv[h][t] = 1.0f / s;
    }
  }
  __syncthreads();

  // stage Ot[c=32h+d][n] = (sum_ch Opart[ch][bh][n0+n][d]) * linv[h][n]
  {
    const int dd = (t & 7) * 4;           // 0..28
    const int nb = t >> 3;                // 0..31
    #pragma unroll
    for (int h = 0; h < NH_; ++h) {
      const u16* ob = Opart + (size_t)(b * NH_ + h) * ((size_t)N_ * HD_)
                    + (size_t)n0 * HD_ + dd;
      #pragma unroll
      for (int p = 0; p < 4; ++p) {
        const int nn = p * 32 + nb;
        f32x4 a = {0.f,0.f,0.f,0.f};
        #pragma unroll
        for (int c = 0; c < NCH_; ++c) {
          const u32x2 ov = *(const u32x2*)(ob
              + (size_t)c * ((size_t)B_ * NH_ * N_ * HD_) + (size_t)nn * HD_);
          a.x += bflo(ov.x); a.y += bfhi(ov.x);
          a.z += bflo(ov.y); a.w += bfhi(ov.y);
        }
        const float iv = linv[h][nn];
        a *= iv;
        Ot[32*h + dd + 0][nn] = f2bf16(a.x);
        Ot[32*h + dd + 1][nn] = f2bf16(a.y);
        Ot[32*h + dd + 2][nn] = f2bf16(a.z);
        Ot[32*h + dd + 3][nn] = f2bf16(a.w);
      }
    }
  }
  __syncthreads();

  // GEMM: thread -> 4 o-rows x 4 n-cols
  const int n4  = (t & 31) * 4;             // 0..124
  const int orow = o0 + (t >> 5) * 4;       // 4 rows
  const float* wp = w + (size_t)orow * C_;
  f32x4 acc0 = {0.f,0.f,0.f,0.f}, acc1 = acc0, acc2 = acc0, acc3 = acc0;
  #pragma unroll 4
  for (int c = 0; c < C_; ++c) {
    const u32x2 ov = *(const u32x2*)(&Ot[c][n4]);
    const f32x4 xv = { bflo(ov.x), bfhi(ov.x), bflo(ov.y), bfhi(ov.y) };
    acc0 += xv * wp[c];
    acc1 += xv * wp[C_ + c];
    acc2 += xv * wp[2*C_ + c];
    acc3 += xv * wp[3*C_ + c];
  }
  const size_t yo = ((size_t)b * C_ + orow) * N_ + n0 + n4;
  const f32x4 xr0 = *(const f32x4*)(x + yo);
  const f32x4 xr1 = *(const f32x4*)(x + yo + N_);
  const f32x4 xr2 = *(const f32x4*)(x + yo + 2*N_);
  const f32x4 xr3 = *(const f32x4*)(x + yo + 3*N_);
  *(f32x4*)(y + yo)        = acc0 + bias[orow]     + xr0;
  *(f32x4*)(y + yo + N_)   = acc1 + bias[orow + 1] + xr1;
  *(f32x4*)(y + yo + 2*N_) = acc2 + bias[orow + 2] + xr2;
  *(f32x4*)(y + yo + 3*N_) = acc3 + bias[orow + 3] + xr3;
}

extern "C" void kernel_launch(void* const* d_in, const int* in_sizes, int n_in,
                              void* d_out, int out_size, void* d_ws, size_t ws_size,
                              hipStream_t stream) {
  const float* x     = (const float*)d_in[0];
  const float* gn_w  = (const float*)d_in[1];
  const float* gn_b  = (const float*)d_in[2];
  const float* qkv_w = (const float*)d_in[3];
  const float* qkv_b = (const float*)d_in[4];
  const float* out_w = (const float*)d_in[5];
  const float* out_b = (const float*)d_in[6];
  float* y = (float*)d_out;

  // ws layout (float offsets):
  //   xn    bf16: [0, 524288)            2 MB
  //   qkvb  bf16: [524288, 2097152)      6 MB  (Q scaled | unused | V)
  //   Kt    bf16: [2097152, 2621440)     2 MB
  //   Opart bf16: [2621440, 4718592)     8 MB  (4 chunks x [b][h][4096][32])
  //   Lpart f32 : [4718592, 4849664)   0.5 MB
  float* ws  = (float*)d_ws;
  u16*   xn   = (u16*)ws;
  u16*   qkvb = (u16*)(ws + 524288);
  u16*   Kt   = (u16*)(ws + 2097152);
  u16*   Opart = (u16*)(ws + 2621440);
  float* Lpart = ws + 4718592;

  k_groupnorm<<<dim3(B_ * GROUPS_), 1024, 0, stream>>>(x, gn_w, gn_b, xn);
  k_gemm_qkv <<<dim3(8, 48, B_),    256, 0, stream>>>(xn, qkv_w, qkv_b, qkvb, Kt);
  k_attn     <<<dim3(16 * NCH_, NH_, B_), 256, 0, stream>>>(qkvb, Kt, Opart, Lpart);
  k_out      <<<dim3(32, 4, B_),    256, 0, stream>>>(Opart, Lpart, out_w, out_b, x, y);
}